// Round 4
// baseline (1312.976 us; speedup 1.0000x reference)
//
#include <hip/hip_runtime.h>
#include <stdint.h>

#define Hn 512
#define Dn 128
#define Nn 64
#define Tn 512
#define NT (Nn*Tn)   // 32768

typedef unsigned int uint;
typedef unsigned short ushort;
typedef unsigned long long u64;

typedef __attribute__((ext_vector_type(4))) float f32x4;

// ---------- ws layout (bytes) ----------
// emitb : 0x0000000  NT*Hn*2  = 32 MB   (exp(emit-rowmax)*rcsg, bf16; cols PERMUTED by k_bexp:
//                     logical c = 32W + nt2*16 + l15  ->  stored 32W + l15*2 + nt2)
// rm    : 0x2000000  NT*4     = 128 KB
// wmat  : 0x2020000  Hn*Dn*4  = 256 KB
// bias  : 0x2060000  Hn*4     = 2 KB
// cs    : 0x2061000  Hn*4     (448/colmax of P)
// rcsg  : 0x2062000  Hn*4     (colmax/448)
// px0s  : 0x2063000  Hn*4     (px[0][j] * cs[j])
// pq    : 0x2070000  16*32*64*8 = 256 KB (P fp8 e4m3, MFMA B-frag order [kt][nt][lane])

__device__ inline float bf2f(ushort u) { union { uint i; float f; } v; v.i = uint(u) << 16; return v.f; }
__device__ inline float ubits(uint u) { union { uint i; float f; } v; v.i = u; return v.f; }
__device__ inline ushort f2bf(float f) {
  union { uint i; float f; } v; v.f = f;
  uint u = v.i;
  uint r = (u + 0x7FFFu + ((u >> 16) & 1u)) >> 16;
  return ushort(r);
}
// e4m3fn decode (non-negative only); finale only
__device__ inline float fp8val(uint b) {
  uint e = (b >> 3) & 15u, m = b & 7u;
  return e ? ldexpf((float)(8u + m), (int)e - 10) : ldexpf((float)m, -9);
}
// pack 8 floats (k-ascending) to 8 e4m3 bytes; SAME helper packs A and B frags,
// so any HW k-permutation within the 32-k tile cancels between operands.
__device__ inline u64 pack8fp8(const float* v, float qs) {
  int lo = 0, hi = 0;
  lo = __builtin_amdgcn_cvt_pk_fp8_f32(v[0] * qs, v[1] * qs, lo, false);
  lo = __builtin_amdgcn_cvt_pk_fp8_f32(v[2] * qs, v[3] * qs, lo, true);
  hi = __builtin_amdgcn_cvt_pk_fp8_f32(v[4] * qs, v[5] * qs, hi, false);
  hi = __builtin_amdgcn_cvt_pk_fp8_f32(v[6] * qs, v[7] * qs, hi, true);
  return (u64)(uint)lo | ((u64)(uint)hi << 32);
}

__global__ void k_prep(const float* __restrict__ py, float* __restrict__ wmat, float* __restrict__ bias) {
  int h = blockIdx.x, d = threadIdx.x;
  float p = py[h * Dn + d];
  float lp = logf(p), l1 = log1pf(-p);
  wmat[h * Dn + d] = lp - l1;
  float v = l1;
  for (int o = 1; o < 64; o <<= 1) v += __shfl_xor(v, o, 64);
  __shared__ float s2[2];
  if ((threadIdx.x & 63) == 0) s2[threadIdx.x >> 6] = v;
  __syncthreads();
  if (threadIdx.x == 0) bias[h] = s2[0] + s2[1];
}

__global__ void k_cs(const float* __restrict__ px, float* __restrict__ cs, float* __restrict__ rcsg,
                     float* __restrict__ px0s) {
  int j = threadIdx.x;  // 512 threads
  float m = 0.f;
#pragma unroll 8
  for (int k = 0; k < Hn; k++) m = fmaxf(m, px[(size_t)k * Hn + j]);
  float c = 448.0f / m;
  cs[j] = c;
  rcsg[j] = m * (1.0f / 448.0f);
  px0s[j] = px[j] * c;   // row 0 of px, pre-scaled by cs
}

// quantize P (col-scaled) into MFMA B-frag order: pq[(kt*32 + nt)*64 + lane]
__global__ __launch_bounds__(256) void k_pq(const float* __restrict__ px, const float* __restrict__ cs,
                                            u64* __restrict__ pq) {
  __shared__ float ksl[32][260];
  int g = blockIdx.x & 1, kt = blockIdx.x >> 1;
  int t = threadIdx.x;
  int k0 = kt * 32;
  for (int i = 0; i < 8; i++) {
    int q = i * 256 + t;
    int row = q >> 6, c4 = q & 63;
    float4 v = *(const float4*)(px + (size_t)(k0 + row) * Hn + g * 256 + c4 * 4);
    ksl[row][c4 * 4 + 0] = v.x; ksl[row][c4 * 4 + 1] = v.y;
    ksl[row][c4 * 4 + 2] = v.z; ksl[row][c4 * 4 + 3] = v.w;
  }
  __syncthreads();
  for (int i = 0; i < 4; i++) {
    int fid = i * 256 + t;
    int ntl = fid >> 6, l = fid & 63;
    int col = ntl * 16 + (l & 15);
    int kr0 = (l >> 4) * 8;
    float csv = cs[g * 256 + col];
    float vv[8];
#pragma unroll
    for (int j = 0; j < 8; j++) vv[j] = ksl[kr0 + j][col];
    pq[(size_t)((kt * 32 + g * 16 + ntl) * 64 + l)] = pack8fp8(vv, csv);
  }
}

__global__ __launch_bounds__(256) void k_emit(const float* __restrict__ A, const float* __restrict__ wmat,
                                              const float* __restrict__ bias, ushort* __restrict__ eb) {
  __shared__ float As[Dn][64];
  __shared__ float Bs[Dn][64];
  int t = threadIdx.x;
  int r0 = blockIdx.y * 64, h0 = blockIdx.x * 64;
  int row = t >> 2, q = t & 3;
  for (int i = 0; i < 8; i++) {
    int ch = q + i * 4;
    float4 a = *(const float4*)(A + (size_t)(r0 + row) * Dn + ch * 4);
    As[ch * 4 + 0][row] = a.x; As[ch * 4 + 1][row] = a.y;
    As[ch * 4 + 2][row] = a.z; As[ch * 4 + 3][row] = a.w;
    float4 b = *(const float4*)(wmat + (size_t)(h0 + row) * Dn + ch * 4);
    Bs[ch * 4 + 0][row] = b.x; Bs[ch * 4 + 1][row] = b.y;
    Bs[ch * 4 + 2][row] = b.z; Bs[ch * 4 + 3][row] = b.w;
  }
  __syncthreads();
  int tx = t & 15, ty = t >> 4;
  float acc[4][4] = {};
  for (int k = 0; k < Dn; k++) {
    float av[4], bv[4];
    *(float4*)av = *(const float4*)&As[k][ty * 4];
    *(float4*)bv = *(const float4*)&Bs[k][tx * 4];
#pragma unroll
    for (int ii = 0; ii < 4; ii++)
#pragma unroll
      for (int jj = 0; jj < 4; jj++) acc[ii][jj] += av[ii] * bv[jj];
  }
  float bsv[4];
  *(float4*)bsv = *(const float4*)(bias + h0 + tx * 4);
#pragma unroll
  for (int ii = 0; ii < 4; ii++) {
    int r = r0 + ty * 4 + ii;
    ushort4 u;
    u.x = f2bf(acc[ii][0] + bsv[0]); u.y = f2bf(acc[ii][1] + bsv[1]);
    u.z = f2bf(acc[ii][2] + bsv[2]); u.w = f2bf(acc[ii][3] + bsv[3]);
    *(ushort4*)(eb + (size_t)r * Hn + h0 + tx * 4) = u;
  }
}

__global__ void k_rowmax(const ushort* __restrict__ eb, float* __restrict__ rm) {
  int r = blockIdx.x, lane = threadIdx.x;
  uint4 u = *(const uint4*)(eb + (size_t)r * Hn + lane * 8);
  float m = bf2f(ushort(u.x & 0xffff));
  m = fmaxf(m, bf2f(ushort(u.x >> 16)));
  m = fmaxf(m, bf2f(ushort(u.y & 0xffff))); m = fmaxf(m, bf2f(ushort(u.y >> 16)));
  m = fmaxf(m, bf2f(ushort(u.z & 0xffff))); m = fmaxf(m, bf2f(ushort(u.z >> 16)));
  m = fmaxf(m, bf2f(ushort(u.w & 0xffff))); m = fmaxf(m, bf2f(ushort(u.w >> 16)));
  for (int o = 1; o < 64; o <<= 1) m = fmaxf(m, __shfl_xor(m, o, 64));
  if (lane == 0) rm[r] = m;
}

// exp(e - rm) * rcsg[c], then permute cols within each 32-block:
// logical c = 32W + nt2*16 + l15  ->  stored at 32W + l15*2 + nt2
// so k_rec loads a wave's 2 cols for one seq with a single b32.
__global__ __launch_bounds__(256) void k_bexp(ushort* __restrict__ eb, const float* __restrict__ rm,
                                              const float* __restrict__ rcsg) {
  int row = blockIdx.x, tr = threadIdx.x;
  ushort* e = eb + (size_t)row * Hn;
  uint u = ((const uint*)e)[tr];
  float m = rm[row];
  int c0 = 2 * tr, c1 = 2 * tr + 1;
  ushort a = f2bf(expf(bf2f(ushort(u & 0xffff)) - m) * rcsg[c0]);
  ushort b = f2bf(expf(bf2f(ushort(u >> 16)) - m) * rcsg[c1]);
  __syncthreads();
  e[(c0 & ~31) + (c0 & 15) * 2 + ((c0 >> 4) & 1)] = a;
  e[(c1 & ~31) + (c1 & 15) * 2 + ((c1 >> 4) & 1)] = b;
}

// 4 WGs x 1024 threads (16 waves, 4 waves/SIMD). Wave w owns n-tiles 2w,2w+1 (cols 32w..32w+31).
// P fp8 B-frags persist in registers (32 u64 = 64 VGPR; launch_bounds(1024,1) guarantees the
// 128-VGPR budget so they DON'T spill — r2's failure mode). Two barriers per step:
//   B0: AfL (quantized alpha frags) published -> MFMA
//   B1: per-seq per-wave partial maxima (sredM) published -> quantize (ut round-trip wave-local)
__global__ __launch_bounds__(1024, 1) void k_rec6(
    const ushort* __restrict__ eb, const float* __restrict__ rm,
    const u64* __restrict__ pq, const float* __restrict__ px0s,
    const int* __restrict__ lens, float* __restrict__ outp) {
  const int grp = blockIdx.x;        // 0..3
  const int t = threadIdx.x;         // 0..1023
  const int w = t >> 6;              // wave 0..15
  const int lane = t & 63, qg = lane >> 4, l15 = lane & 15;

  __shared__ float ut[16][516];      // u values fp32 [seq][logical col]
  __shared__ u64 AfL[16 * 64];       // alpha A-frags [kt][lane]
  __shared__ float sredM[16][20];    // per-seq per-wave partial max
  __shared__ float rmsL[16];
  __shared__ int lenl[16];

  // ---- persistent P fragments: wave w owns n-tiles 2w, 2w+1 ----
  u64 PR[32];
#pragma unroll
  for (int kt = 0; kt < 16; kt++) {
    PR[kt * 2 + 0] = pq[(size_t)((kt * 32 + 2 * w + 0) * 64 + lane)];
    PR[kt * 2 + 1] = pq[(size_t)((kt * 32 + 2 * w + 1) * 64 + lane)];
  }

  if (t < 16) lenl[t] = lens[grp * 16 + t];

  const size_t seqstride = (size_t)Tn * Hn;

  // ---- init: u0 = px0s[c] * e'[c]  (e' = exp(..)*rcsg, px0s = px0*cs; product = px0*e) ----
  {
    float p0 = px0s[32 * w + l15], p1 = px0s[32 * w + 16 + l15];
    float mx[4];
#pragma unroll
    for (int r = 0; r < 4; r++) {
      int s = qg * 4 + r;
      uint ev = *(const uint*)(eb + (size_t)(grp * 16 + s) * seqstride + 32 * w + l15 * 2);
      float u0 = p0 * ubits(ev << 16);
      float u1 = p1 * ubits(ev & 0xffff0000u);
      ut[s][32 * w + l15] = u0;
      ut[s][32 * w + 16 + l15] = u1;
      mx[r] = fmaxf(u0, u1);
    }
#pragma unroll
    for (int o = 1; o < 16; o <<= 1) {
      mx[0] = fmaxf(mx[0], __shfl_xor(mx[0], o, 64));
      mx[1] = fmaxf(mx[1], __shfl_xor(mx[1], o, 64));
      mx[2] = fmaxf(mx[2], __shfl_xor(mx[2], o, 64));
      mx[3] = fmaxf(mx[3], __shfl_xor(mx[3], o, 64));
    }
    if (l15 == 0) {
#pragma unroll
      for (int r = 0; r < 4; r++) sredM[qg * 4 + r][w] = mx[r];
    }
  }
  __syncthreads();
  const int t_end = lenl[15];
  const int lenq = lenl[l15];
  float L2acc;
  u64 myfrag;

  // ---- combine gm (seq=l15) + step-0 quantize (kt = w, wave-local ut cols) ----
  {
    float4 g0 = *(const float4*)&sredM[l15][0];
    float4 g1 = *(const float4*)&sredM[l15][4];
    float4 g2 = *(const float4*)&sredM[l15][8];
    float4 g3 = *(const float4*)&sredM[l15][12];
    float gm = fmaxf(fmaxf(fmaxf(fmaxf(g0.x, g0.y), fmaxf(g0.z, g0.w)),
                           fmaxf(fmaxf(g1.x, g1.y), fmaxf(g1.z, g1.w))),
                     fmaxf(fmaxf(fmaxf(g2.x, g2.y), fmaxf(g2.z, g2.w)),
                           fmaxf(fmaxf(g3.x, g3.y), fmaxf(g3.z, g3.w))));
    L2acc = __log2f(gm);
    float qs = 448.0f * __builtin_amdgcn_rcpf(gm);
    float4 A = *(const float4*)&ut[l15][32 * w + qg * 8];
    float4 B = *(const float4*)&ut[l15][32 * w + qg * 8 + 4];
    float vv[8] = {A.x, A.y, A.z, A.w, B.x, B.y, B.z, B.w};
    myfrag = pack8fp8(vv, qs);
    AfL[w * 64 + lane] = myfrag;
  }

  // ---- emit prefetch for ts=1: 4 seqs x 1 b32 (pair of cols) ----
  const ushort* ep[4];
  uint bp[4];
#pragma unroll
  for (int r = 0; r < 4; r++) {
    ep[r] = eb + ((size_t)(grp * 16 + qg * 4 + r) * Tn + 1) * Hn + 32 * w + l15 * 2;
    bp[r] = *(const uint*)ep[r];
    ep[r] += Hn;
  }

  // ---- recursion: 2 barriers/step ----
  for (int ts = 1; ts < t_end; ts++) {
    __syncthreads();  // B0: AfL published
    // prefetch emit(ts+1); consumed next iteration
    uint bq[4];
#pragma unroll
    for (int r = 0; r < 4; r++) { bq[r] = *(const uint*)ep[r]; ep[r] += Hn; }

    // MFMA: 16 k-tiles x 2 n-tiles, B from registers
    f32x4 ac0 = {0.f, 0.f, 0.f, 0.f}, ac1 = {0.f, 0.f, 0.f, 0.f};
#pragma unroll
    for (int kt = 0; kt < 16; kt++) {
      u64 af = AfL[kt * 64 + lane];
      ac0 = __builtin_amdgcn_mfma_f32_16x16x32_fp8_fp8((long)af, (long)PR[kt * 2 + 0], ac0, 0, 0, 0);
      ac1 = __builtin_amdgcn_mfma_f32_16x16x32_fp8_fp8((long)af, (long)PR[kt * 2 + 1], ac1, 0, 0, 0);
    }

    // epilogue: u = acc * e' (rcs folded into e'); wave-partial per-seq max via shfl
    float mx[4];
#pragma unroll
    for (int r = 0; r < 4; r++) {
      int s = qg * 4 + r;
      uint ev = bp[r];
      float u0 = ac0[r] * ubits(ev << 16);
      float u1 = ac1[r] * ubits(ev & 0xffff0000u);
      ut[s][32 * w + l15] = u0;
      ut[s][32 * w + 16 + l15] = u1;
      mx[r] = fmaxf(u0, u1);
    }
#pragma unroll
    for (int o = 1; o < 16; o <<= 1) {
      mx[0] = fmaxf(mx[0], __shfl_xor(mx[0], o, 64));
      mx[1] = fmaxf(mx[1], __shfl_xor(mx[1], o, 64));
      mx[2] = fmaxf(mx[2], __shfl_xor(mx[2], o, 64));
      mx[3] = fmaxf(mx[3], __shfl_xor(mx[3], o, 64));
    }
    if (l15 == 0) {
#pragma unroll
      for (int r = 0; r < 4; r++) sredM[qg * 4 + r][w] = mx[r];
    }
    __syncthreads();  // B1: sredM visible; ut round-trip is wave-local

    // combine gm for seq l15; quantize kt=w frag from own wave's ut cols
    {
      float4 g0 = *(const float4*)&sredM[l15][0];
      float4 g1 = *(const float4*)&sredM[l15][4];
      float4 g2 = *(const float4*)&sredM[l15][8];
      float4 g3 = *(const float4*)&sredM[l15][12];
      float4 A = *(const float4*)&ut[l15][32 * w + qg * 8];
      float4 B = *(const float4*)&ut[l15][32 * w + qg * 8 + 4];
      float gm = fmaxf(fmaxf(fmaxf(fmaxf(g0.x, g0.y), fmaxf(g0.z, g0.w)),
                             fmaxf(fmaxf(g1.x, g1.y), fmaxf(g1.z, g1.w))),
                       fmaxf(fmaxf(fmaxf(g2.x, g2.y), fmaxf(g2.z, g2.w)),
                             fmaxf(fmaxf(g3.x, g3.y), fmaxf(g3.z, g3.w))));
      if (ts < lenq) {
        L2acc += __log2f(gm);
        float qs = 448.0f * __builtin_amdgcn_rcpf(gm);
        float vv[8] = {A.x, A.y, A.z, A.w, B.x, B.y, B.z, B.w};
        myfrag = pack8fp8(vv, qs);
        AfL[w * 64 + lane] = myfrag;
      }
    }
#pragma unroll
    for (int r = 0; r < 4; r++) bp[r] = bq[r];
  }

  // ---- finale ----
  __syncthreads();
  // S partials: myfrag = (seq l15, k-cols 32w + qg*8 .. +8), last active pack
  {
    float ps = 0.f;
#pragma unroll
    for (int j = 0; j < 8; j++) ps += fp8val((uint)(myfrag >> (8 * j)) & 0xffu);
    ps += __shfl_xor(ps, 16, 64);
    ps += __shfl_xor(ps, 32, 64);
    if (lane < 16) sredM[lane][w] = ps;
  }
  // rm sums: wave w handles seq w
  {
    const float* rp = rm + (size_t)(grp * 16 + w) * Tn;
    int ls = lenl[w];
    float rs = 0.f;
#pragma unroll
    for (int k = 0; k < 8; k++) {
      int idx = lane + 64 * k;
      float v = rp[idx];
      rs += (idx < ls) ? v : 0.f;
    }
#pragma unroll
    for (int o = 1; o < 64; o <<= 1) rs += __shfl_xor(rs, o, 64);
    if (lane == 0) rmsL[w] = rs;
  }
  __syncthreads();
  if (t < 16) {  // wave 0, lane t holds L2acc for seq t
    float Ss = 0.f;
#pragma unroll
    for (int ww = 0; ww < 16; ww++) Ss += sredM[t][ww];
    outp[grp * 16 + t] = 0.6931471805599453f * L2acc - (float)lenq * 6.104793232414985f
                         + logf(Ss) + rmsL[t];
  }
}

extern "C" void kernel_launch(void* const* d_in, const int* in_sizes, int n_in,
                              void* d_out, int out_size, void* d_ws, size_t ws_size,
                              hipStream_t stream) {
  const float* seq = (const float*)d_in[0];
  const int* lens = (const int*)d_in[1];
  const float* px = (const float*)d_in[2];
  const float* py = (const float*)d_in[3];
  char* ws = (char*)d_ws;
  ushort* emitb = (ushort*)(ws + 0x0000000);
  float* rm     = (float*)(ws + 0x2000000);
  float* wmat   = (float*)(ws + 0x2020000);
  float* bias   = (float*)(ws + 0x2060000);
  float* cs     = (float*)(ws + 0x2061000);
  float* rcsg   = (float*)(ws + 0x2062000);
  float* px0s   = (float*)(ws + 0x2063000);
  u64* pq       = (u64*)(ws + 0x2070000);
  float* outp   = (float*)d_out;

  hipLaunchKernelGGL(k_prep, dim3(512), dim3(128), 0, stream, py, wmat, bias);
  hipLaunchKernelGGL(k_cs, dim3(1), dim3(512), 0, stream, px, cs, rcsg, px0s);
  hipLaunchKernelGGL(k_pq, dim3(32), dim3(256), 0, stream, px, cs, pq);
  hipLaunchKernelGGL(k_emit, dim3(8, 512), dim3(256), 0, stream, seq, wmat, bias, emitb);
  hipLaunchKernelGGL(k_rowmax, dim3(NT), dim3(64), 0, stream, emitb, rm);
  hipLaunchKernelGGL(k_bexp, dim3(NT), dim3(256), 0, stream, emitb, rm, rcsg);
  hipLaunchKernelGGL(k_rec6, dim3(4), dim3(1024), 0, stream, emitb, rm, pq, px0s, lens, outp);
}

// Round 5
// 1011.062 us; speedup vs baseline: 1.2986x; 1.2986x over previous
//
#include <hip/hip_runtime.h>
#include <stdint.h>

#define Hn 512
#define Dn 128
#define Nn 64
#define Tn 512
#define NT (Nn*Tn)   // 32768

typedef unsigned int uint;
typedef unsigned short ushort;
typedef unsigned long long u64;

typedef __attribute__((ext_vector_type(4))) float f32x4;
typedef __attribute__((ext_vector_type(8))) int i32x8;

// ---------- ws layout (bytes) ----------
// emitb : 0x0000000  NT*Hn*2  = 32 MB   (exp(emit-rowmax)*rcsg, bf16; cols PERMUTED by k_bexp:
//                     logical c = 64W + nt*16 + j -> stored 64W + j*4 + nt)
// rm    : 0x2000000  NT*4     = 128 KB
// wmat  : 0x2020000  Hn*Dn*4  = 256 KB
// bias  : 0x2060000  Hn*4     = 2 KB
// cs    : 0x2061000  Hn*4     (448/colmax of P)
// rcsg  : 0x2062000  Hn*4     (colmax/448)
// px0s  : 0x2063000  Hn*4     (px[0][j] * cs[j])
// pq    : 0x2070000  256 KB   (P fp8 e4m3, K=128 MFMA B-frag order [w][kt*4+ntl][lane][32B])

__device__ inline float bf2f(ushort u) { union { uint i; float f; } v; v.i = uint(u) << 16; return v.f; }
__device__ inline ushort f2bf(float f) {
  union { uint i; float f; } v; v.f = f;
  uint u = v.i;
  uint r = (u + 0x7FFFu + ((u >> 16) & 1u)) >> 16;
  return ushort(r);
}
// e4m3fn decode (non-negative only); finale only
__device__ inline float fp8val(uint b) {
  uint e = (b >> 3) & 15u, m = b & 7u;
  return e ? ldexpf((float)(8u + m), (int)e - 10) : ldexpf((float)m, -9);
}
// pack 8 floats (k-ascending) to 8 e4m3 bytes; SAME helper packs A and B frags,
// so any HW k-permutation cancels between operands (scales are uniform 1.0).
__device__ inline u64 pack8fp8(const float* v, float qs) {
  int lo = 0, hi = 0;
  lo = __builtin_amdgcn_cvt_pk_fp8_f32(v[0] * qs, v[1] * qs, lo, false);
  lo = __builtin_amdgcn_cvt_pk_fp8_f32(v[2] * qs, v[3] * qs, lo, true);
  hi = __builtin_amdgcn_cvt_pk_fp8_f32(v[4] * qs, v[5] * qs, hi, false);
  hi = __builtin_amdgcn_cvt_pk_fp8_f32(v[6] * qs, v[7] * qs, hi, true);
  return (u64)(uint)lo | ((u64)(uint)hi << 32);
}

__global__ void k_prep(const float* __restrict__ py, float* __restrict__ wmat, float* __restrict__ bias) {
  int h = blockIdx.x, d = threadIdx.x;
  float p = py[h * Dn + d];
  float lp = logf(p), l1 = log1pf(-p);
  wmat[h * Dn + d] = lp - l1;
  float v = l1;
  for (int o = 1; o < 64; o <<= 1) v += __shfl_xor(v, o, 64);
  __shared__ float s2[2];
  if ((threadIdx.x & 63) == 0) s2[threadIdx.x >> 6] = v;
  __syncthreads();
  if (threadIdx.x == 0) bias[h] = s2[0] + s2[1];
}

__global__ void k_cs(const float* __restrict__ px, float* __restrict__ cs, float* __restrict__ rcsg,
                     float* __restrict__ px0s) {
  int j = threadIdx.x;  // 512 threads
  float m = 0.f;
#pragma unroll 8
  for (int k = 0; k < Hn; k++) m = fmaxf(m, px[(size_t)k * Hn + j]);
  float c = 448.0f / m;
  cs[j] = c;
  rcsg[j] = m * (1.0f / 448.0f);
  px0s[j] = px[j] * c;   // row 0 of px, pre-scaled by cs
}

// quantize P (col-scaled) into K=128 MFMA B-frag order:
// frag (ntg, kt): lane (qg,c15) holds bytes jj=0..31 <-> k = kt*128 + qg*32 + jj, col = ntg*16 + c15
// pq u64 index: ((( (ntg>>2)*16 + kt*4 + (ntg&3) )*64 + lane)*4 + d   (d = jj>>3)
__global__ __launch_bounds__(256) void k_pq(const float* __restrict__ px, const float* __restrict__ cs,
                                            u64* __restrict__ pq) {
  __shared__ float ksl[512][17];   // 34 KB, padded stride
  int ntg = blockIdx.x;            // 0..31
  int t = threadIdx.x;
  for (int i = 0; i < 8; i++) {
    int q = i * 256 + t;           // float4 id over 512x16
    int row = q >> 2, c4 = q & 3;
    float4 v = *(const float4*)(px + (size_t)row * Hn + ntg * 16 + c4 * 4);
    ksl[row][c4 * 4 + 0] = v.x; ksl[row][c4 * 4 + 1] = v.y;
    ksl[row][c4 * 4 + 2] = v.z; ksl[row][c4 * 4 + 3] = v.w;
  }
  __syncthreads();
  int kt = t >> 6, lane = t & 63, qg = lane >> 4, c15 = lane & 15;
  float csv = cs[ntg * 16 + c15];
  int kbase = kt * 128 + qg * 32;
  size_t base = ((size_t)(((ntg >> 2) * 16 + kt * 4 + (ntg & 3)) * 64 + lane)) * 4;
#pragma unroll
  for (int d = 0; d < 4; d++) {
    float vv[8];
#pragma unroll
    for (int b = 0; b < 8; b++) vv[b] = ksl[kbase + d * 8 + b][c15];
    pq[base + d] = pack8fp8(vv, csv);
  }
}

__global__ __launch_bounds__(256) void k_emit(const float* __restrict__ A, const float* __restrict__ wmat,
                                              const float* __restrict__ bias, ushort* __restrict__ eb) {
  __shared__ float As[Dn][64];
  __shared__ float Bs[Dn][64];
  int t = threadIdx.x;
  int r0 = blockIdx.y * 64, h0 = blockIdx.x * 64;
  int row = t >> 2, q = t & 3;
  for (int i = 0; i < 8; i++) {
    int ch = q + i * 4;
    float4 a = *(const float4*)(A + (size_t)(r0 + row) * Dn + ch * 4);
    As[ch * 4 + 0][row] = a.x; As[ch * 4 + 1][row] = a.y;
    As[ch * 4 + 2][row] = a.z; As[ch * 4 + 3][row] = a.w;
    float4 b = *(const float4*)(wmat + (size_t)(h0 + row) * Dn + ch * 4);
    Bs[ch * 4 + 0][row] = b.x; Bs[ch * 4 + 1][row] = b.y;
    Bs[ch * 4 + 2][row] = b.z; Bs[ch * 4 + 3][row] = b.w;
  }
  __syncthreads();
  int tx = t & 15, ty = t >> 4;
  float acc[4][4] = {};
  for (int k = 0; k < Dn; k++) {
    float av[4], bv[4];
    *(float4*)av = *(const float4*)&As[k][ty * 4];
    *(float4*)bv = *(const float4*)&Bs[k][tx * 4];
#pragma unroll
    for (int ii = 0; ii < 4; ii++)
#pragma unroll
      for (int jj = 0; jj < 4; jj++) acc[ii][jj] += av[ii] * bv[jj];
  }
  float bsv[4];
  *(float4*)bsv = *(const float4*)(bias + h0 + tx * 4);
#pragma unroll
  for (int ii = 0; ii < 4; ii++) {
    int r = r0 + ty * 4 + ii;
    ushort4 u;
    u.x = f2bf(acc[ii][0] + bsv[0]); u.y = f2bf(acc[ii][1] + bsv[1]);
    u.z = f2bf(acc[ii][2] + bsv[2]); u.w = f2bf(acc[ii][3] + bsv[3]);
    *(ushort4*)(eb + (size_t)r * Hn + h0 + tx * 4) = u;
  }
}

__global__ void k_rowmax(const ushort* __restrict__ eb, float* __restrict__ rm) {
  int r = blockIdx.x, lane = threadIdx.x;
  uint4 u = *(const uint4*)(eb + (size_t)r * Hn + lane * 8);
  float m = bf2f(ushort(u.x & 0xffff));
  m = fmaxf(m, bf2f(ushort(u.x >> 16)));
  m = fmaxf(m, bf2f(ushort(u.y & 0xffff))); m = fmaxf(m, bf2f(ushort(u.y >> 16)));
  m = fmaxf(m, bf2f(ushort(u.z & 0xffff))); m = fmaxf(m, bf2f(ushort(u.z >> 16)));
  m = fmaxf(m, bf2f(ushort(u.w & 0xffff))); m = fmaxf(m, bf2f(ushort(u.w >> 16)));
  for (int o = 1; o < 64; o <<= 1) m = fmaxf(m, __shfl_xor(m, o, 64));
  if (lane == 0) rm[r] = m;
}

// exp(e - rm) * rcsg[c], then permute within each 64-block:
// logical c = 64W + nt*16 + j  ->  stored at 64W + j*4 + nt  (b64 at j*4 loads nt=0..3)
__global__ __launch_bounds__(256) void k_bexp(ushort* __restrict__ eb, const float* __restrict__ rm,
                                              const float* __restrict__ rcsg) {
  int row = blockIdx.x, tr = threadIdx.x;
  ushort* e = eb + (size_t)row * Hn;
  uint u = ((const uint*)e)[tr];
  float m = rm[row];
  int c0 = 2 * tr, c1 = 2 * tr + 1;
  ushort a = f2bf(expf(bf2f(ushort(u & 0xffff)) - m) * rcsg[c0]);
  ushort b = f2bf(expf(bf2f(ushort(u >> 16)) - m) * rcsg[c1]);
  __syncthreads();
  e[(c0 & ~63) + (c0 & 15) * 4 + ((c0 & 63) >> 4)] = a;
  e[(c1 & ~63) + (c1 & 15) * 4 + ((c1 & 63) >> 4)] = b;
}

// 4 WGs x 512 threads (8 waves, 2/SIMD). Wave w owns cols 64w..64w+63 (4 n-tiles).
// MFMA: mfma_scale_f32_16x16x128_f8f6f4 with unit scales (2.25x the K=32 fp8 rate).
// P B-frags persist in registers (128 VGPR). Alpha A-frag image in LDS, XOR-swizzled
// (blk ^ (seq&7)) -> every LDS access in the kernel is conflict-free.
// Two barriers per step: B0 (AfI published -> MFMA), B1 (sredM published -> quantize).
__global__ __launch_bounds__(512, 2) void k_rec7(
    const ushort* __restrict__ eb, const float* __restrict__ rm,
    const u64* __restrict__ pq, const float* __restrict__ px0s,
    const int* __restrict__ lens, float* __restrict__ outp) {
  const int grp = blockIdx.x;        // 0..3
  const int t = threadIdx.x;         // 0..511
  const int w = t >> 6;              // wave 0..7
  const int lane = t & 63, qg = lane >> 4, l15 = lane & 15;
  const int sx = l15 & 7;

  __shared__ float ut[16][516];      // u values fp32 [seq][logical col]  (33 KB)
  __shared__ uint4 AfI[512];         // alpha fp8 image: [seq][32 blk of 16B, blk^=(seq&7)] (8 KB)
  __shared__ float sredM[16][12];    // per-seq per-wave partial max
  __shared__ float rmsL[16];
  __shared__ int lenl[16];

  // ---- persistent P fragments: wave w -> n-tiles 4w..4w+3, f = kt*4 + ntl ----
  i32x8 PRv[16];
  {
    const uint4* pqv = (const uint4*)pq;
#pragma unroll
    for (int f = 0; f < 16; f++) {
      uint4 p0 = pqv[((size_t)(w * 16 + f) * 64 + lane) * 2 + 0];
      uint4 p1 = pqv[((size_t)(w * 16 + f) * 64 + lane) * 2 + 1];
      i32x8 v = {(int)p0.x, (int)p0.y, (int)p0.z, (int)p0.w,
                 (int)p1.x, (int)p1.y, (int)p1.z, (int)p1.w};
      PRv[f] = v;
    }
  }

  if (t < 16) lenl[t] = lens[grp * 16 + t];
  const size_t seqstride = (size_t)Tn * Hn;

  // ---- init: u0 = px0s[c] * e'[c]  (e' = exp*rcsg, px0s = px0*cs; cs*rcsg = 1) ----
  {
    float p0 = px0s[w * 64 + l15];
    float p1 = px0s[w * 64 + 16 + l15];
    float p2 = px0s[w * 64 + 32 + l15];
    float p3 = px0s[w * 64 + 48 + l15];
    float mx[4];
#pragma unroll
    for (int r = 0; r < 4; r++) {
      int s = qg * 4 + r;
      u64 ev = *(const u64*)(eb + (size_t)(grp * 16 + s) * seqstride + w * 64 + l15 * 4);
      float u0 = p0 * bf2f(ushort(ev & 0xffff));
      float u1 = p1 * bf2f(ushort((ev >> 16) & 0xffff));
      float u2 = p2 * bf2f(ushort((ev >> 32) & 0xffff));
      float u3 = p3 * bf2f(ushort(ev >> 48));
      ut[s][w * 64 + l15] = u0;
      ut[s][w * 64 + 16 + l15] = u1;
      ut[s][w * 64 + 32 + l15] = u2;
      ut[s][w * 64 + 48 + l15] = u3;
      mx[r] = fmaxf(fmaxf(u0, u1), fmaxf(u2, u3));
    }
#pragma unroll
    for (int o = 1; o < 16; o <<= 1) {
      mx[0] = fmaxf(mx[0], __shfl_xor(mx[0], o, 64));
      mx[1] = fmaxf(mx[1], __shfl_xor(mx[1], o, 64));
      mx[2] = fmaxf(mx[2], __shfl_xor(mx[2], o, 64));
      mx[3] = fmaxf(mx[3], __shfl_xor(mx[3], o, 64));
    }
    if (l15 == 0) {
#pragma unroll
      for (int r = 0; r < 4; r++) sredM[qg * 4 + r][w] = mx[r];
    }
  }
  __syncthreads();
  const int t_end = lenl[15];
  const int lenq = lenl[l15];
  float L2acc;

  // ---- step-0: combine gm (seq=l15), quantize 16 bytes (seq l15, k blk = w*4+qg) ----
  {
    float4 g0 = *(const float4*)&sredM[l15][0];
    float4 g1 = *(const float4*)&sredM[l15][4];
    float gm = fmaxf(fmaxf(fmaxf(g0.x, g0.y), fmaxf(g0.z, g0.w)),
                     fmaxf(fmaxf(g1.x, g1.y), fmaxf(g1.z, g1.w)));
    L2acc = __log2f(gm);
    float qs = 448.0f * __builtin_amdgcn_rcpf(gm);
    float4 A = *(const float4*)&ut[l15][w * 64 + qg * 16 + 0];
    float4 B = *(const float4*)&ut[l15][w * 64 + qg * 16 + 4];
    float4 C = *(const float4*)&ut[l15][w * 64 + qg * 16 + 8];
    float4 D = *(const float4*)&ut[l15][w * 64 + qg * 16 + 12];
    float v0[8] = {A.x, A.y, A.z, A.w, B.x, B.y, B.z, B.w};
    float v1[8] = {C.x, C.y, C.z, C.w, D.x, D.y, D.z, D.w};
    u64 lo = pack8fp8(v0, qs), hi = pack8fp8(v1, qs);
    uint4 fr = {(uint)lo, (uint)(lo >> 32), (uint)hi, (uint)(hi >> 32)};
    AfI[l15 * 32 + ((w * 4 + qg) ^ sx)] = fr;
  }

  // ---- emit prefetch for ts=1 (4 seqs x b64) ----
  const ushort* ep[4];
  u64 bp[4];
#pragma unroll
  for (int r = 0; r < 4; r++) {
    ep[r] = eb + ((size_t)(grp * 16 + qg * 4 + r) * Tn + 1) * Hn + w * 64 + l15 * 4;
    bp[r] = *(const u64*)ep[r];
    ep[r] += Hn;
  }

  // ---- recursion: 2 barriers/step ----
  for (int ts = 1; ts < t_end; ts++) {
    __syncthreads();  // B0: AfI published
    u64 bq[4];
#pragma unroll
    for (int r = 0; r < 4; r++) { bq[r] = *(const u64*)ep[r]; ep[r] += Hn; }

    // MFMA: 4 k-blocks (K=128 each) x 4 n-tiles, B from registers, unit e8m0 scales
    f32x4 ac0 = {0.f, 0.f, 0.f, 0.f}, ac1 = {0.f, 0.f, 0.f, 0.f};
    f32x4 ac2 = {0.f, 0.f, 0.f, 0.f}, ac3 = {0.f, 0.f, 0.f, 0.f};
#pragma unroll
    for (int kt = 0; kt < 4; kt++) {
      uint4 a0 = AfI[l15 * 32 + ((kt * 8 + qg * 2 + 0) ^ sx)];
      uint4 a1 = AfI[l15 * 32 + ((kt * 8 + qg * 2 + 1) ^ sx)];
      i32x8 af = {(int)a0.x, (int)a0.y, (int)a0.z, (int)a0.w,
                  (int)a1.x, (int)a1.y, (int)a1.z, (int)a1.w};
      ac0 = __builtin_amdgcn_mfma_scale_f32_16x16x128_f8f6f4(
          af, PRv[kt * 4 + 0], ac0, 0, 0, 0, 0x7F7F7F7F, 0, 0x7F7F7F7F);
      ac1 = __builtin_amdgcn_mfma_scale_f32_16x16x128_f8f6f4(
          af, PRv[kt * 4 + 1], ac1, 0, 0, 0, 0x7F7F7F7F, 0, 0x7F7F7F7F);
      ac2 = __builtin_amdgcn_mfma_scale_f32_16x16x128_f8f6f4(
          af, PRv[kt * 4 + 2], ac2, 0, 0, 0, 0x7F7F7F7F, 0, 0x7F7F7F7F);
      ac3 = __builtin_amdgcn_mfma_scale_f32_16x16x128_f8f6f4(
          af, PRv[kt * 4 + 3], ac3, 0, 0, 0, 0x7F7F7F7F, 0, 0x7F7F7F7F);
    }

    // epilogue: u = acc * e' (col scale folded into e'); per-seq wave-partial max
    float mx[4];
#pragma unroll
    for (int r = 0; r < 4; r++) {
      int s = qg * 4 + r;
      u64 ev = bp[r];
      float u0 = ac0[r] * bf2f(ushort(ev & 0xffff));
      float u1 = ac1[r] * bf2f(ushort((ev >> 16) & 0xffff));
      float u2 = ac2[r] * bf2f(ushort((ev >> 32) & 0xffff));
      float u3 = ac3[r] * bf2f(ushort(ev >> 48));
      ut[s][w * 64 + l15] = u0;
      ut[s][w * 64 + 16 + l15] = u1;
      ut[s][w * 64 + 32 + l15] = u2;
      ut[s][w * 64 + 48 + l15] = u3;
      mx[r] = fmaxf(fmaxf(u0, u1), fmaxf(u2, u3));
    }
#pragma unroll
    for (int o = 1; o < 16; o <<= 1) {
      mx[0] = fmaxf(mx[0], __shfl_xor(mx[0], o, 64));
      mx[1] = fmaxf(mx[1], __shfl_xor(mx[1], o, 64));
      mx[2] = fmaxf(mx[2], __shfl_xor(mx[2], o, 64));
      mx[3] = fmaxf(mx[3], __shfl_xor(mx[3], o, 64));
    }
    if (l15 == 0) {
#pragma unroll
      for (int r = 0; r < 4; r++) sredM[qg * 4 + r][w] = mx[r];
    }
    __syncthreads();  // B1: sredM visible; ut round-trip is wave-local

    // quantize: seq l15, k-block w*4+qg (cols w*64+qg*16..+16)
    if (ts < lenq) {
      float4 g0 = *(const float4*)&sredM[l15][0];
      float4 g1 = *(const float4*)&sredM[l15][4];
      float gm = fmaxf(fmaxf(fmaxf(g0.x, g0.y), fmaxf(g0.z, g0.w)),
                       fmaxf(fmaxf(g1.x, g1.y), fmaxf(g1.z, g1.w)));
      L2acc += __log2f(gm);
      float qs = 448.0f * __builtin_amdgcn_rcpf(gm);
      float4 A = *(const float4*)&ut[l15][w * 64 + qg * 16 + 0];
      float4 B = *(const float4*)&ut[l15][w * 64 + qg * 16 + 4];
      float4 C = *(const float4*)&ut[l15][w * 64 + qg * 16 + 8];
      float4 D = *(const float4*)&ut[l15][w * 64 + qg * 16 + 12];
      float v0[8] = {A.x, A.y, A.z, A.w, B.x, B.y, B.z, B.w};
      float v1[8] = {C.x, C.y, C.z, C.w, D.x, D.y, D.z, D.w};
      u64 lo = pack8fp8(v0, qs), hi = pack8fp8(v1, qs);
      uint4 fr = {(uint)lo, (uint)(lo >> 32), (uint)hi, (uint)(hi >> 32)};
      AfI[l15 * 32 + ((w * 4 + qg) ^ sx)] = fr;
    }
#pragma unroll
    for (int r = 0; r < 4; r++) bp[r] = bq[r];
  }

  // ---- finale ----
  __syncthreads();
  // S partials: read back my quantize slot (frozen seqs kept their last active frag)
  {
    uint4 fr = AfI[l15 * 32 + ((w * 4 + qg) ^ sx)];
    float ps = 0.f;
    uint dw[4] = {fr.x, fr.y, fr.z, fr.w};
#pragma unroll
    for (int d = 0; d < 4; d++)
#pragma unroll
      for (int j = 0; j < 4; j++) ps += fp8val((dw[d] >> (8 * j)) & 0xffu);
    ps += __shfl_xor(ps, 16, 64);
    ps += __shfl_xor(ps, 32, 64);
    if (lane < 16) sredM[lane][w] = ps;
  }
  // rm sums: wave w handles seqs 2w (lanes 0..31), 2w+1 (lanes 32..63)
  {
    int sq = 2 * w + (lane >> 5), tl = lane & 31;
    const float* rp = rm + (size_t)(grp * 16 + sq) * Tn;
    int ls = lenl[sq];
    float rs = 0.f;
#pragma unroll
    for (int k = 0; k < 16; k++) {
      int idx = tl + 32 * k;
      float v = rp[idx];
      rs += (idx < ls) ? v : 0.f;
    }
#pragma unroll
    for (int o = 1; o < 32; o <<= 1) rs += __shfl_xor(rs, o, 64);
    if ((lane & 31) == 0) rmsL[sq] = rs;
  }
  __syncthreads();
  if (t < 16) {  // wave 0, lane t: holds L2acc for seq t (w=0, qg=0, l15=t)
    float4 s0 = *(const float4*)&sredM[t][0];
    float4 s1 = *(const float4*)&sredM[t][4];
    float Ss = (s0.x + s0.y) + (s0.z + s0.w) + (s1.x + s1.y) + (s1.z + s1.w);
    outp[grp * 16 + t] = 0.6931471805599453f * L2acc - (float)lenq * 6.104793232414985f
                         + logf(Ss) + rmsL[t];
  }
}

extern "C" void kernel_launch(void* const* d_in, const int* in_sizes, int n_in,
                              void* d_out, int out_size, void* d_ws, size_t ws_size,
                              hipStream_t stream) {
  const float* seq = (const float*)d_in[0];
  const int* lens = (const int*)d_in[1];
  const float* px = (const float*)d_in[2];
  const float* py = (const float*)d_in[3];
  char* ws = (char*)d_ws;
  ushort* emitb = (ushort*)(ws + 0x0000000);
  float* rm     = (float*)(ws + 0x2000000);
  float* wmat   = (float*)(ws + 0x2020000);
  float* bias   = (float*)(ws + 0x2060000);
  float* cs     = (float*)(ws + 0x2061000);
  float* rcsg   = (float*)(ws + 0x2062000);
  float* px0s   = (float*)(ws + 0x2063000);
  u64* pq       = (u64*)(ws + 0x2070000);
  float* outp   = (float*)d_out;

  hipLaunchKernelGGL(k_prep, dim3(512), dim3(128), 0, stream, py, wmat, bias);
  hipLaunchKernelGGL(k_cs, dim3(1), dim3(512), 0, stream, px, cs, rcsg, px0s);
  hipLaunchKernelGGL(k_pq, dim3(32), dim3(256), 0, stream, px, cs, pq);
  hipLaunchKernelGGL(k_emit, dim3(8, 512), dim3(256), 0, stream, seq, wmat, bias, emitb);
  hipLaunchKernelGGL(k_rowmax, dim3(NT), dim3(64), 0, stream, emitb, rm);
  hipLaunchKernelGGL(k_bexp, dim3(NT), dim3(256), 0, stream, emitb, rm, rcsg);
  hipLaunchKernelGGL(k_rec7, dim3(4), dim3(512), 0, stream, emitb, rm, pq, px0s, lens, outp);
}

// Round 6
// 819.706 us; speedup vs baseline: 1.6018x; 1.2334x over previous
//
#include <hip/hip_runtime.h>
#include <stdint.h>

#define Hn 512
#define Dn 128
#define Nn 64
#define Tn 512
#define NT (Nn*Tn)   // 32768

typedef unsigned int uint;
typedef unsigned short ushort;
typedef unsigned long long u64;

typedef __attribute__((ext_vector_type(4))) float f32x4;
typedef __attribute__((ext_vector_type(8))) int i32x8;

// lgkm-only barrier: orders all LDS traffic across the WG without draining vmcnt,
// so global prefetch loads stay in flight across barriers.
#define WG_BARRIER() asm volatile("s_waitcnt lgkmcnt(0)\n\ts_barrier" ::: "memory")

// ---------- ws layout (bytes) ----------
// emitb : 0x0000000  NT*Hn*2  = 32 MB  (exp(emit-rowmax)*rcsg, bf16; cols PERMUTED by k_bexp:
//                    logical c (mt,qg,r fields) -> stored with qg<->mt swapped, so each lane's
//                    16 epilogue values are one contiguous 32B run)
// rm    : 0x2000000  NT*4     = 128 KB
// wmat  : 0x2020000  Hn*Dn*4  = 256 KB
// bias  : 0x2060000  Hn*4     = 2 KB
// cs    : 0x2061000  Hn*4     (448/colmax of P)
// rcsg  : 0x2062000  Hn*4     (colmax/448)
// px0sp : 0x2063000  Hn*4     (px[0][j] * cs[j], stored PERMUTED like emitb)
// pq    : 0x2070000  256 KB   (P fp8 e4m3, K=128 MFMA frag order [w][kt*4+mt][lane][32B])

__device__ inline float bf2f(ushort u) { union { uint i; float f; } v; v.i = uint(u) << 16; return v.f; }
__device__ inline float ubits(uint u) { union { uint i; float f; } v; v.i = u; return v.f; }
__device__ inline ushort f2bf(float f) {
  union { uint i; float f; } v; v.f = f;
  uint u = v.i;
  uint r = (u + 0x7FFFu + ((u >> 16) & 1u)) >> 16;
  return ushort(r);
}
// e4m3fn decode (non-negative only); finale only
__device__ inline float fp8val(uint b) {
  uint e = (b >> 3) & 15u, m = b & 7u;
  return e ? ldexpf((float)(8u + m), (int)e - 10) : ldexpf((float)m, -9);
}
// pack 8 floats (k-ascending) to 8 e4m3 bytes; SAME helper packs A and B frags,
// so any HW k-permutation cancels between operands (scales uniform 1.0).
__device__ inline u64 pack8fp8(const float* v, float qs) {
  int lo = 0, hi = 0;
  lo = __builtin_amdgcn_cvt_pk_fp8_f32(v[0] * qs, v[1] * qs, lo, false);
  lo = __builtin_amdgcn_cvt_pk_fp8_f32(v[2] * qs, v[3] * qs, lo, true);
  hi = __builtin_amdgcn_cvt_pk_fp8_f32(v[4] * qs, v[5] * qs, hi, false);
  hi = __builtin_amdgcn_cvt_pk_fp8_f32(v[6] * qs, v[7] * qs, hi, true);
  return (u64)(uint)lo | ((u64)(uint)hi << 32);
}
// col permutation used by k_bexp / k_cs: swap the (mt, qg) 2-bit fields
__device__ inline int permcol(int c) {
  return (c & ~63) | ((c & 12) << 2) | ((c & 48) >> 2) | (c & 3);
}

__global__ void k_prep(const float* __restrict__ py, float* __restrict__ wmat, float* __restrict__ bias) {
  int h = blockIdx.x, d = threadIdx.x;
  float p = py[h * Dn + d];
  float lp = logf(p), l1 = log1pf(-p);
  wmat[h * Dn + d] = lp - l1;
  float v = l1;
  for (int o = 1; o < 64; o <<= 1) v += __shfl_xor(v, o, 64);
  __shared__ float s2[2];
  if ((threadIdx.x & 63) == 0) s2[threadIdx.x >> 6] = v;
  __syncthreads();
  if (threadIdx.x == 0) bias[h] = s2[0] + s2[1];
}

__global__ void k_cs(const float* __restrict__ px, float* __restrict__ cs, float* __restrict__ rcsg,
                     float* __restrict__ px0sp) {
  int j = threadIdx.x;  // 512 threads
  float m = 0.f;
#pragma unroll 8
  for (int k = 0; k < Hn; k++) m = fmaxf(m, px[(size_t)k * Hn + j]);
  float c = 448.0f / m;
  cs[j] = c;
  rcsg[j] = m * (1.0f / 448.0f);
  px0sp[permcol(j)] = px[j] * c;   // row 0 of px, pre-scaled, PERMUTED
}

// quantize P (col-scaled) into K=128 MFMA frag order (now the A operand):
// frag (ntg, kt): lane (qg,c15) holds bytes jj=0..31 <-> k = kt*128 + qg*32 + jj, col = ntg*16 + c15
// pq u64 index: (((ntg>>2)*16 + kt*4 + (ntg&3))*64 + lane)*4 + d   (d = jj>>3)
__global__ __launch_bounds__(256) void k_pq(const float* __restrict__ px, const float* __restrict__ cs,
                                            u64* __restrict__ pq) {
  __shared__ float ksl[512][17];   // 34 KB, padded stride
  int ntg = blockIdx.x;            // 0..31
  int t = threadIdx.x;
  for (int i = 0; i < 8; i++) {
    int q = i * 256 + t;           // float4 id over 512x16
    int row = q >> 2, c4 = q & 3;
    float4 v = *(const float4*)(px + (size_t)row * Hn + ntg * 16 + c4 * 4);
    ksl[row][c4 * 4 + 0] = v.x; ksl[row][c4 * 4 + 1] = v.y;
    ksl[row][c4 * 4 + 2] = v.z; ksl[row][c4 * 4 + 3] = v.w;
  }
  __syncthreads();
  int kt = t >> 6, lane = t & 63, qg = lane >> 4, c15 = lane & 15;
  float csv = cs[ntg * 16 + c15];
  int kbase = kt * 128 + qg * 32;
  size_t base = ((size_t)(((ntg >> 2) * 16 + kt * 4 + (ntg & 3)) * 64 + lane)) * 4;
#pragma unroll
  for (int d = 0; d < 4; d++) {
    float vv[8];
#pragma unroll
    for (int b = 0; b < 8; b++) vv[b] = ksl[kbase + d * 8 + b][c15];
    pq[base + d] = pack8fp8(vv, csv);
  }
}

__global__ __launch_bounds__(256) void k_emit(const float* __restrict__ A, const float* __restrict__ wmat,
                                              const float* __restrict__ bias, ushort* __restrict__ eb) {
  __shared__ float As[Dn][64];
  __shared__ float Bs[Dn][64];
  int t = threadIdx.x;
  int r0 = blockIdx.y * 64, h0 = blockIdx.x * 64;
  int row = t >> 2, q = t & 3;
  for (int i = 0; i < 8; i++) {
    int ch = q + i * 4;
    float4 a = *(const float4*)(A + (size_t)(r0 + row) * Dn + ch * 4);
    As[ch * 4 + 0][row] = a.x; As[ch * 4 + 1][row] = a.y;
    As[ch * 4 + 2][row] = a.z; As[ch * 4 + 3][row] = a.w;
    float4 b = *(const float4*)(wmat + (size_t)(h0 + row) * Dn + ch * 4);
    Bs[ch * 4 + 0][row] = b.x; Bs[ch * 4 + 1][row] = b.y;
    Bs[ch * 4 + 2][row] = b.z; Bs[ch * 4 + 3][row] = b.w;
  }
  __syncthreads();
  int tx = t & 15, ty = t >> 4;
  float acc[4][4] = {};
  for (int k = 0; k < Dn; k++) {
    float av[4], bv[4];
    *(float4*)av = *(const float4*)&As[k][ty * 4];
    *(float4*)bv = *(const float4*)&Bs[k][tx * 4];
#pragma unroll
    for (int ii = 0; ii < 4; ii++)
#pragma unroll
      for (int jj = 0; jj < 4; jj++) acc[ii][jj] += av[ii] * bv[jj];
  }
  float bsv[4];
  *(float4*)bsv = *(const float4*)(bias + h0 + tx * 4);
#pragma unroll
  for (int ii = 0; ii < 4; ii++) {
    int r = r0 + ty * 4 + ii;
    ushort4 u;
    u.x = f2bf(acc[ii][0] + bsv[0]); u.y = f2bf(acc[ii][1] + bsv[1]);
    u.z = f2bf(acc[ii][2] + bsv[2]); u.w = f2bf(acc[ii][3] + bsv[3]);
    *(ushort4*)(eb + (size_t)r * Hn + h0 + tx * 4) = u;
  }
}

__global__ void k_rowmax(const ushort* __restrict__ eb, float* __restrict__ rm) {
  int r = blockIdx.x, lane = threadIdx.x;
  uint4 u = *(const uint4*)(eb + (size_t)r * Hn + lane * 8);
  float m = bf2f(ushort(u.x & 0xffff));
  m = fmaxf(m, bf2f(ushort(u.x >> 16)));
  m = fmaxf(m, bf2f(ushort(u.y & 0xffff))); m = fmaxf(m, bf2f(ushort(u.y >> 16)));
  m = fmaxf(m, bf2f(ushort(u.z & 0xffff))); m = fmaxf(m, bf2f(ushort(u.z >> 16)));
  m = fmaxf(m, bf2f(ushort(u.w & 0xffff))); m = fmaxf(m, bf2f(ushort(u.w >> 16)));
  for (int o = 1; o < 64; o <<= 1) m = fmaxf(m, __shfl_xor(m, o, 64));
  if (lane == 0) rm[r] = m;
}

// exp(e - rm) * rcsg[c], stored at permcol(c): each k_rec lane's 16 values contiguous (32B).
__global__ __launch_bounds__(256) void k_bexp(ushort* __restrict__ eb, const float* __restrict__ rm,
                                              const float* __restrict__ rcsg) {
  int row = blockIdx.x, tr = threadIdx.x;
  ushort* e = eb + (size_t)row * Hn;
  uint u = ((const uint*)e)[tr];
  float m = rm[row];
  int c0 = 2 * tr;
  ushort a = f2bf(expf(bf2f(ushort(u & 0xffff)) - m) * rcsg[c0]);
  ushort b = f2bf(expf(bf2f(ushort(u >> 16)) - m) * rcsg[c0 + 1]);
  __syncthreads();
  int p0 = permcol(c0);   // p1 = p0+1 (bit0 passes through)
  ((uint*)e)[p0 >> 1] = uint(a) | (uint(b) << 16);
}

// 4 WGs x 512 threads (8 waves). OPERAND-SWAPPED recursion: D = P(A) x alpha(B).
// Lane (qg,l15) of wave w owns seq l15, cols {w*64 + mt*16 + qg*4 + r}.
// P frags persist in registers (128 VGPR). Alpha image BfI in LDS (33-uint4 row pitch ->
// conflict-free phases). Two lgkm-only barriers per step.
__global__ __launch_bounds__(512, 2) void k_rec8(
    const ushort* __restrict__ eb, const float* __restrict__ rm,
    const u64* __restrict__ pq, const float* __restrict__ px0sp,
    const int* __restrict__ lens, float* __restrict__ outp) {
  const int grp = blockIdx.x;        // 0..3
  const int t = threadIdx.x;         // 0..511
  const int w = t >> 6;              // wave 0..7
  const int lane = t & 63, qg = lane >> 4, l15 = lane & 15;

  __shared__ float ut[16][516];      // u values fp32 [seq][logical col] (33 KB)
  __shared__ uint4 BfI[16 * 33];     // alpha fp8 image [seq][32 slots of 16B + 1 pad] (8.25 KB)
  __shared__ float sredM[16][12];    // per-seq per-wave partial max
  __shared__ float rmsL[16];
  __shared__ int lenl[16];

  // ---- persistent P fragments (A operand): wave w -> m-tiles (Pcol tiles) 4w..4w+3 ----
  i32x8 PRv[16];
  {
    const uint4* pqv = (const uint4*)pq;
#pragma unroll
    for (int f = 0; f < 16; f++) {
      uint4 p0 = pqv[((size_t)(w * 16 + f) * 64 + lane) * 2 + 0];
      uint4 p1 = pqv[((size_t)(w * 16 + f) * 64 + lane) * 2 + 1];
      i32x8 v = {(int)p0.x, (int)p0.y, (int)p0.z, (int)p0.w,
                 (int)p1.x, (int)p1.y, (int)p1.z, (int)p1.w};
      PRv[f] = v;
    }
  }

  if (t < 16) lenl[t] = lens[grp * 16 + t];
  const size_t seqstride = (size_t)Tn * Hn;
  const ushort* myrow = eb + (size_t)(grp * 16 + l15) * seqstride + w * 64 + qg * 16;

  // ---- init: u0 = px0sp * e' (both permuted identically; cs*rcsg = 1) ----
  {
    uint4 e0 = *(const uint4*)myrow;
    uint4 e1 = *(const uint4*)(myrow + 8);
    uint eu[8] = {e0.x, e0.y, e0.z, e0.w, e1.x, e1.y, e1.z, e1.w};
    float mxv = 0.f;
#pragma unroll
    for (int m = 0; m < 4; m++) {
      float4 pv = *(const float4*)(px0sp + w * 64 + qg * 16 + m * 4);
      float4 uv;
      uv.x = pv.x * ubits(eu[2 * m] << 16);
      uv.y = pv.y * ubits(eu[2 * m] & 0xffff0000u);
      uv.z = pv.z * ubits(eu[2 * m + 1] << 16);
      uv.w = pv.w * ubits(eu[2 * m + 1] & 0xffff0000u);
      *(float4*)&ut[l15][w * 64 + m * 16 + qg * 4] = uv;
      mxv = fmaxf(mxv, fmaxf(fmaxf(uv.x, uv.y), fmaxf(uv.z, uv.w)));
    }
    mxv = fmaxf(mxv, __shfl_xor(mxv, 16, 64));
    mxv = fmaxf(mxv, __shfl_xor(mxv, 32, 64));
    if (qg == 0) sredM[l15][w] = mxv;
  }
  WG_BARRIER();
  const int t_end = lenl[15];
  const int lenq = lenl[l15];
  float L2acc;
  u64 myf0, myf1;

  // ---- step-0: combine gm (seq=l15), quantize 16B slot (w*4+qg) ----
  {
    float4 g0 = *(const float4*)&sredM[l15][0];
    float4 g1 = *(const float4*)&sredM[l15][4];
    float gm = fmaxf(fmaxf(fmaxf(g0.x, g0.y), fmaxf(g0.z, g0.w)),
                     fmaxf(fmaxf(g1.x, g1.y), fmaxf(g1.z, g1.w)));
    L2acc = __log2f(gm);
    float qs = 448.0f * __builtin_amdgcn_rcpf(gm);
    float4 A = *(const float4*)&ut[l15][(w * 4 + qg) * 16 + 0];
    float4 B = *(const float4*)&ut[l15][(w * 4 + qg) * 16 + 4];
    float4 C = *(const float4*)&ut[l15][(w * 4 + qg) * 16 + 8];
    float4 D = *(const float4*)&ut[l15][(w * 4 + qg) * 16 + 12];
    float v0[8] = {A.x, A.y, A.z, A.w, B.x, B.y, B.z, B.w};
    float v1[8] = {C.x, C.y, C.z, C.w, D.x, D.y, D.z, D.w};
    myf0 = pack8fp8(v0, qs);
    myf1 = pack8fp8(v1, qs);
    BfI[l15 * 33 + w * 4 + qg] =
        (uint4){(uint)myf0, (uint)(myf0 >> 32), (uint)myf1, (uint)(myf1 >> 32)};
  }

  // ---- emit prefetch: bp = row ts=1 (one contiguous 32B per lane) ----
  const ushort* epp = myrow + Hn;
  uint4 bpA = *(const uint4*)epp;
  uint4 bpB = *(const uint4*)(epp + 8);
  epp += Hn;

  // ---- recursion: 2 lgkm-only barriers/step ----
  for (int ts = 1; ts < t_end; ts++) {
    WG_BARRIER();  // BAR0: BfI published
    uint4 bqA = *(const uint4*)epp;
    uint4 bqB = *(const uint4*)(epp + 8);
    epp += Hn;

    // MFMA: 4 k-blocks (K=128) x 4 m-tiles; A=P from regs, B=alpha from LDS
    f32x4 ac0 = {0.f, 0.f, 0.f, 0.f}, ac1 = {0.f, 0.f, 0.f, 0.f};
    f32x4 ac2 = {0.f, 0.f, 0.f, 0.f}, ac3 = {0.f, 0.f, 0.f, 0.f};
#pragma unroll
    for (int kb = 0; kb < 4; kb++) {
      uint4 b0 = BfI[l15 * 33 + kb * 8 + qg * 2 + 0];
      uint4 b1 = BfI[l15 * 33 + kb * 8 + qg * 2 + 1];
      i32x8 bf = {(int)b0.x, (int)b0.y, (int)b0.z, (int)b0.w,
                  (int)b1.x, (int)b1.y, (int)b1.z, (int)b1.w};
      ac0 = __builtin_amdgcn_mfma_scale_f32_16x16x128_f8f6f4(
          PRv[kb * 4 + 0], bf, ac0, 0, 0, 0, 0x7F7F7F7F, 0, 0x7F7F7F7F);
      ac1 = __builtin_amdgcn_mfma_scale_f32_16x16x128_f8f6f4(
          PRv[kb * 4 + 1], bf, ac1, 0, 0, 0, 0x7F7F7F7F, 0, 0x7F7F7F7F);
      ac2 = __builtin_amdgcn_mfma_scale_f32_16x16x128_f8f6f4(
          PRv[kb * 4 + 2], bf, ac2, 0, 0, 0, 0x7F7F7F7F, 0, 0x7F7F7F7F);
      ac3 = __builtin_amdgcn_mfma_scale_f32_16x16x128_f8f6f4(
          PRv[kb * 4 + 3], bf, ac3, 0, 0, 0, 0x7F7F7F7F, 0, 0x7F7F7F7F);
    }

    // epilogue: u = acc * e'; in-register per-seq max; 4x ds_write_b128
    float mxv;
    {
      uint eu[8] = {bpA.x, bpA.y, bpA.z, bpA.w, bpB.x, bpB.y, bpB.z, bpB.w};
      float4 uv0, uv1, uv2, uv3;
      uv0.x = ac0[0] * ubits(eu[0] << 16);  uv0.y = ac0[1] * ubits(eu[0] & 0xffff0000u);
      uv0.z = ac0[2] * ubits(eu[1] << 16);  uv0.w = ac0[3] * ubits(eu[1] & 0xffff0000u);
      uv1.x = ac1[0] * ubits(eu[2] << 16);  uv1.y = ac1[1] * ubits(eu[2] & 0xffff0000u);
      uv1.z = ac1[2] * ubits(eu[3] << 16);  uv1.w = ac1[3] * ubits(eu[3] & 0xffff0000u);
      uv2.x = ac2[0] * ubits(eu[4] << 16);  uv2.y = ac2[1] * ubits(eu[4] & 0xffff0000u);
      uv2.z = ac2[2] * ubits(eu[5] << 16);  uv2.w = ac2[3] * ubits(eu[5] & 0xffff0000u);
      uv3.x = ac3[0] * ubits(eu[6] << 16);  uv3.y = ac3[1] * ubits(eu[6] & 0xffff0000u);
      uv3.z = ac3[2] * ubits(eu[7] << 16);  uv3.w = ac3[3] * ubits(eu[7] & 0xffff0000u);
      *(float4*)&ut[l15][w * 64 + 0 * 16 + qg * 4] = uv0;
      *(float4*)&ut[l15][w * 64 + 1 * 16 + qg * 4] = uv1;
      *(float4*)&ut[l15][w * 64 + 2 * 16 + qg * 4] = uv2;
      *(float4*)&ut[l15][w * 64 + 3 * 16 + qg * 4] = uv3;
      float m01 = fmaxf(fmaxf(fmaxf(uv0.x, uv0.y), fmaxf(uv0.z, uv0.w)),
                        fmaxf(fmaxf(uv1.x, uv1.y), fmaxf(uv1.z, uv1.w)));
      float m23 = fmaxf(fmaxf(fmaxf(uv2.x, uv2.y), fmaxf(uv2.z, uv2.w)),
                        fmaxf(fmaxf(uv3.x, uv3.y), fmaxf(uv3.z, uv3.w)));
      mxv = fmaxf(m01, m23);
    }
    mxv = fmaxf(mxv, __shfl_xor(mxv, 16, 64));
    mxv = fmaxf(mxv, __shfl_xor(mxv, 32, 64));
    if (qg == 0) sredM[l15][w] = mxv;
    WG_BARRIER();  // BAR1: ut + sredM published

    // quantize: seq l15, 16B slot (w*4+qg)
    if (ts < lenq) {
      float4 g0 = *(const float4*)&sredM[l15][0];
      float4 g1 = *(const float4*)&sredM[l15][4];
      float gm = fmaxf(fmaxf(fmaxf(g0.x, g0.y), fmaxf(g0.z, g0.w)),
                       fmaxf(fmaxf(g1.x, g1.y), fmaxf(g1.z, g1.w)));
      L2acc += __log2f(gm);
      float qs = 448.0f * __builtin_amdgcn_rcpf(gm);
      float4 A = *(const float4*)&ut[l15][(w * 4 + qg) * 16 + 0];
      float4 B = *(const float4*)&ut[l15][(w * 4 + qg) * 16 + 4];
      float4 C = *(const float4*)&ut[l15][(w * 4 + qg) * 16 + 8];
      float4 D = *(const float4*)&ut[l15][(w * 4 + qg) * 16 + 12];
      float v0[8] = {A.x, A.y, A.z, A.w, B.x, B.y, B.z, B.w};
      float v1[8] = {C.x, C.y, C.z, C.w, D.x, D.y, D.z, D.w};
      myf0 = pack8fp8(v0, qs);
      myf1 = pack8fp8(v1, qs);
      BfI[l15 * 33 + w * 4 + qg] =
          (uint4){(uint)myf0, (uint)(myf0 >> 32), (uint)myf1, (uint)(myf1 >> 32)};
    }
    bpA = bqA; bpB = bqB;
  }

  // ---- finale ----
  WG_BARRIER();
  {
    float ps = 0.f;
#pragma unroll
    for (int j = 0; j < 8; j++) {
      ps += fp8val((uint)(myf0 >> (8 * j)) & 0xffu);
      ps += fp8val((uint)(myf1 >> (8 * j)) & 0xffu);
    }
    ps += __shfl_xor(ps, 16, 64);
    ps += __shfl_xor(ps, 32, 64);
    if (qg == 0) sredM[l15][w] = ps;  // partial sum over this wave's k-window, seq l15
  }
  // rm sums: wave w handles seqs 2w (lanes 0..31), 2w+1 (lanes 32..63)
  {
    int sq = 2 * w + (lane >> 5), tl = lane & 31;
    const float* rp = rm + (size_t)(grp * 16 + sq) * Tn;
    int ls = lenl[sq];
    float rs = 0.f;
#pragma unroll
    for (int k = 0; k < 16; k++) {
      int idx = tl + 32 * k;
      float v = rp[idx];
      rs += (idx < ls) ? v : 0.f;
    }
#pragma unroll
    for (int o = 1; o < 32; o <<= 1) rs += __shfl_xor(rs, o, 64);
    if ((lane & 31) == 0) rmsL[sq] = rs;
  }
  __syncthreads();
  if (t < 16) {  // wave 0, qg 0, l15 = t: holds L2acc/lenq for seq t
    float4 s0 = *(const float4*)&sredM[t][0];
    float4 s1 = *(const float4*)&sredM[t][4];
    float Ss = (s0.x + s0.y) + (s0.z + s0.w) + (s1.x + s1.y) + (s1.z + s1.w);
    outp[grp * 16 + t] = 0.6931471805599453f * L2acc - (float)lenq * 6.104793232414985f
                         + logf(Ss) + rmsL[t];
  }
}

extern "C" void kernel_launch(void* const* d_in, const int* in_sizes, int n_in,
                              void* d_out, int out_size, void* d_ws, size_t ws_size,
                              hipStream_t stream) {
  const float* seq = (const float*)d_in[0];
  const int* lens = (const int*)d_in[1];
  const float* px = (const float*)d_in[2];
  const float* py = (const float*)d_in[3];
  char* ws = (char*)d_ws;
  ushort* emitb = (ushort*)(ws + 0x0000000);
  float* rm     = (float*)(ws + 0x2000000);
  float* wmat   = (float*)(ws + 0x2020000);
  float* bias   = (float*)(ws + 0x2060000);
  float* cs     = (float*)(ws + 0x2061000);
  float* rcsg   = (float*)(ws + 0x2062000);
  float* px0sp  = (float*)(ws + 0x2063000);
  u64* pq       = (u64*)(ws + 0x2070000);
  float* outp   = (float*)d_out;

  hipLaunchKernelGGL(k_prep, dim3(512), dim3(128), 0, stream, py, wmat, bias);
  hipLaunchKernelGGL(k_cs, dim3(1), dim3(512), 0, stream, px, cs, rcsg, px0sp);
  hipLaunchKernelGGL(k_pq, dim3(32), dim3(256), 0, stream, px, cs, pq);
  hipLaunchKernelGGL(k_emit, dim3(8, 512), dim3(256), 0, stream, seq, wmat, bias, emitb);
  hipLaunchKernelGGL(k_rowmax, dim3(NT), dim3(64), 0, stream, emitb, rm);
  hipLaunchKernelGGL(k_bexp, dim3(NT), dim3(256), 0, stream, emitb, rm, rcsg);
  hipLaunchKernelGGL(k_rec8, dim3(4), dim3(512), 0, stream, emitb, rm, pq, px0sp, lens, outp);
}

// Round 7
// 756.552 us; speedup vs baseline: 1.7355x; 1.0835x over previous
//
#include <hip/hip_runtime.h>
#include <stdint.h>

#define Hn 512
#define Dn 128
#define Nn 64
#define Tn 512
#define NT (Nn*Tn)   // 32768

typedef unsigned int uint;
typedef unsigned short ushort;
typedef unsigned long long u64;

typedef __attribute__((ext_vector_type(4))) float f32x4;
typedef __attribute__((ext_vector_type(8))) int i32x8;

// lgkm-only barrier: orders all LDS traffic across the WG without draining vmcnt,
// so global prefetch loads stay in flight across barriers.
#define WG_BARRIER() asm volatile("s_waitcnt lgkmcnt(0)\n\ts_barrier" ::: "memory")

// ---------- ws layout (bytes) ----------
// emitb : 0x0000000  NT*Hn*2  = 32 MB  (exp(emit-rowmax)*rcsg, bf16; cols PERMUTED:
//                    each k_rec lane's 16 values are one contiguous 32B run)
// rm    : 0x2000000  NT*4     = 128 KB
// wmat  : 0x2020000  Hn*Dn*4  = 256 KB
// bias  : 0x2060000  Hn*4     = 2 KB
// cs    : 0x2061000  Hn*4     (448/colmax of P)
// rcsg  : 0x2062000  Hn*4     (colmax/448)
// px0sp : 0x2063000  Hn*4     (px[0][j]*cs[j], stored PERMUTED like emitb)
// pq    : 0x2070000  256 KB   (P fp8 e4m3, K=128 MFMA A-frags with sigma-permuted byte order
//                    matching the epilogue lane layout: [w][kb*4+mt][lane][32B])

__device__ inline float bf2f(ushort u) { union { uint i; float f; } v; v.i = uint(u) << 16; return v.f; }
__device__ inline float ubits(uint u) { union { uint i; float f; } v; v.i = u; return v.f; }
__device__ inline ushort f2bf(float f) {
  union { uint i; float f; } v; v.f = f;
  uint u = v.i;
  uint r = (u + 0x7FFFu + ((u >> 16) & 1u)) >> 16;
  return ushort(r);
}
// e4m3fn decode (non-negative only); finale only
__device__ inline float fp8val(uint b) {
  uint e = (b >> 3) & 15u, m = b & 7u;
  return e ? ldexpf((float)(8u + m), (int)e - 10) : ldexpf((float)m, -9);
}
// pack 8 floats to 8 e4m3 bytes; the (position -> k) convention is defined by k_pq's
// sigma gather, applied identically to A and B so HW pairing cancels.
__device__ inline u64 pack8fp8(const float* v, float qs) {
  int lo = 0, hi = 0;
  lo = __builtin_amdgcn_cvt_pk_fp8_f32(v[0] * qs, v[1] * qs, lo, false);
  lo = __builtin_amdgcn_cvt_pk_fp8_f32(v[2] * qs, v[3] * qs, lo, true);
  hi = __builtin_amdgcn_cvt_pk_fp8_f32(v[4] * qs, v[5] * qs, hi, false);
  hi = __builtin_amdgcn_cvt_pk_fp8_f32(v[6] * qs, v[7] * qs, hi, true);
  return (u64)(uint)lo | ((u64)(uint)hi << 32);
}
// col permutation for emitb/px0sp: swap (mt, qg) 2-bit fields within each 64-block
__device__ inline int permcol(int c) {
  return (c & ~63) | ((c & 12) << 2) | ((c & 48) >> 2) | (c & 3);
}

__global__ void k_prep(const float* __restrict__ py, float* __restrict__ wmat, float* __restrict__ bias) {
  int h = blockIdx.x, d = threadIdx.x;
  float p = py[h * Dn + d];
  float lp = logf(p), l1 = log1pf(-p);
  wmat[h * Dn + d] = lp - l1;
  float v = l1;
  for (int o = 1; o < 64; o <<= 1) v += __shfl_xor(v, o, 64);
  __shared__ float s2[2];
  if ((threadIdx.x & 63) == 0) s2[threadIdx.x >> 6] = v;
  __syncthreads();
  if (threadIdx.x == 0) bias[h] = s2[0] + s2[1];
}

__global__ void k_cs(const float* __restrict__ px, float* __restrict__ cs, float* __restrict__ rcsg,
                     float* __restrict__ px0sp) {
  int j = threadIdx.x;  // 512 threads
  float m = 0.f;
#pragma unroll 8
  for (int k = 0; k < Hn; k++) m = fmaxf(m, px[(size_t)k * Hn + j]);
  float c = 448.0f / m;
  cs[j] = c;
  rcsg[j] = m * (1.0f / 448.0f);
  px0sp[permcol(j)] = px[j] * c;   // row 0 of px, pre-scaled, PERMUTED
}

// quantize P (col-scaled) into sigma-permuted K=128 A-frag order:
// byte (qa, jj) of block kb <-> k = kb*128 + (qa>>1)*64 + ((jj>>2)&3)*16 + (qa&1)*8 + (jj>>4)*4 + (jj&3)
// This matches the epilogue lane's natural value order, so alpha needs NO transpose.
__global__ __launch_bounds__(256) void k_pq(const float* __restrict__ px, const float* __restrict__ cs,
                                            u64* __restrict__ pq) {
  __shared__ float ksl[512][17];   // 34 KB, padded stride
  int ntg = blockIdx.x;            // global m-tile 0..31
  int t = threadIdx.x;
  for (int i = 0; i < 8; i++) {
    int q = i * 256 + t;           // float4 id over 512x16
    int row = q >> 2, c4 = q & 3;
    float4 v = *(const float4*)(px + (size_t)row * Hn + ntg * 16 + c4 * 4);
    ksl[row][c4 * 4 + 0] = v.x; ksl[row][c4 * 4 + 1] = v.y;
    ksl[row][c4 * 4 + 2] = v.z; ksl[row][c4 * 4 + 3] = v.w;
  }
  __syncthreads();
  int kb = t >> 6, lane = t & 63, qa = lane >> 4, c15 = lane & 15;
  float csv = cs[ntg * 16 + c15];
  int kbase = kb * 128 + (qa >> 1) * 64 + (qa & 1) * 8;
  size_t base = ((size_t)(((ntg >> 2) * 16 + kb * 4 + (ntg & 3)) * 64 + lane)) * 4;
#pragma unroll
  for (int d = 0; d < 4; d++) {
    float vv[8];
#pragma unroll
    for (int b = 0; b < 8; b++) {
      int jj = d * 8 + b;
      int kk = kbase + (((jj >> 2) & 3) << 4) + ((jj >> 4) << 2) + (jj & 3);
      vv[b] = ksl[kk][c15];
    }
    pq[base + d] = pack8fp8(vv, csv);
  }
}

__global__ __launch_bounds__(256) void k_emit(const float* __restrict__ A, const float* __restrict__ wmat,
                                              const float* __restrict__ bias, ushort* __restrict__ eb) {
  __shared__ float As[Dn][64];
  __shared__ float Bs[Dn][64];
  int t = threadIdx.x;
  int r0 = blockIdx.y * 64, h0 = blockIdx.x * 64;
  int row = t >> 2, q = t & 3;
  for (int i = 0; i < 8; i++) {
    int ch = q + i * 4;
    float4 a = *(const float4*)(A + (size_t)(r0 + row) * Dn + ch * 4);
    As[ch * 4 + 0][row] = a.x; As[ch * 4 + 1][row] = a.y;
    As[ch * 4 + 2][row] = a.z; As[ch * 4 + 3][row] = a.w;
    float4 b = *(const float4*)(wmat + (size_t)(h0 + row) * Dn + ch * 4);
    Bs[ch * 4 + 0][row] = b.x; Bs[ch * 4 + 1][row] = b.y;
    Bs[ch * 4 + 2][row] = b.z; Bs[ch * 4 + 3][row] = b.w;
  }
  __syncthreads();
  int tx = t & 15, ty = t >> 4;
  float acc[4][4] = {};
  for (int k = 0; k < Dn; k++) {
    float av[4], bv[4];
    *(float4*)av = *(const float4*)&As[k][ty * 4];
    *(float4*)bv = *(const float4*)&Bs[k][tx * 4];
#pragma unroll
    for (int ii = 0; ii < 4; ii++)
#pragma unroll
      for (int jj = 0; jj < 4; jj++) acc[ii][jj] += av[ii] * bv[jj];
  }
  float bsv[4];
  *(float4*)bsv = *(const float4*)(bias + h0 + tx * 4);
#pragma unroll
  for (int ii = 0; ii < 4; ii++) {
    int r = r0 + ty * 4 + ii;
    ushort4 u;
    u.x = f2bf(acc[ii][0] + bsv[0]); u.y = f2bf(acc[ii][1] + bsv[1]);
    u.z = f2bf(acc[ii][2] + bsv[2]); u.w = f2bf(acc[ii][3] + bsv[3]);
    *(ushort4*)(eb + (size_t)r * Hn + h0 + tx * 4) = u;
  }
}

// FUSED rowmax + exp + rcsg-scale + permute store. One wave per row -> in-wave
// lockstep means all reads complete before any write; no barrier needed.
__global__ __launch_bounds__(64) void k_bexp2(ushort* __restrict__ eb, float* __restrict__ rm,
                                              const float* __restrict__ rcsg) {
  int row = blockIdx.x, lane = threadIdx.x;
  ushort* e = eb + (size_t)row * Hn;
  uint4 u = ((const uint4*)e)[lane];   // cols lane*8 .. lane*8+7
  float f[8];
  f[0] = bf2f(ushort(u.x & 0xffff)); f[1] = bf2f(ushort(u.x >> 16));
  f[2] = bf2f(ushort(u.y & 0xffff)); f[3] = bf2f(ushort(u.y >> 16));
  f[4] = bf2f(ushort(u.z & 0xffff)); f[5] = bf2f(ushort(u.z >> 16));
  f[6] = bf2f(ushort(u.w & 0xffff)); f[7] = bf2f(ushort(u.w >> 16));
  float m = fmaxf(fmaxf(fmaxf(f[0], f[1]), fmaxf(f[2], f[3])),
                  fmaxf(fmaxf(f[4], f[5]), fmaxf(f[6], f[7])));
  for (int o = 1; o < 64; o <<= 1) m = fmaxf(m, __shfl_xor(m, o, 64));
  if (lane == 0) rm[row] = m;
#pragma unroll
  for (int i = 0; i < 4; i++) {
    int c0 = lane * 8 + 2 * i;
    ushort a = f2bf(expf(f[2 * i] - m) * rcsg[c0]);
    ushort b = f2bf(expf(f[2 * i + 1] - m) * rcsg[c0 + 1]);
    ((uint*)e)[permcol(c0) >> 1] = uint(a) | (uint(b) << 16);
  }
}

// 4 WGs x 512 threads (8 waves). D = P(A) x alpha(B), sigma-permuted k-order.
// Lane (qg,l15) of wave w owns seq l15, cols {w*64 + mt*16 + qg*4 + r} — and packs
// those SAME 16 registers directly into its 16B BfI slot (no ut array, no transpose).
// Cross-wave traffic per step: BfI (8.25 KB image) + sredM (48B max exchange).
__global__ __launch_bounds__(512, 2) void k_rec9(
    const ushort* __restrict__ eb, const float* __restrict__ rm,
    const u64* __restrict__ pq, const float* __restrict__ px0sp,
    const int* __restrict__ lens, float* __restrict__ outp) {
  const int grp = blockIdx.x;        // 0..3
  const int t = threadIdx.x;         // 0..511
  const int w = t >> 6;              // wave 0..7
  const int lane = t & 63, qg = lane >> 4, l15 = lane & 15;

  __shared__ uint BfI[16 * 132];     // alpha fp8 image, row pitch 132 words (8.25 KB)
  __shared__ float sredM[16][12];    // per-seq per-wave partial max
  __shared__ float rmsL[16];
  __shared__ int lenl[16];

  // ---- persistent P fragments (A operand): wave w -> m-tiles 4w..4w+3 ----
  i32x8 PRv[16];
  {
    const uint4* pqv = (const uint4*)pq;
#pragma unroll
    for (int f = 0; f < 16; f++) {
      uint4 p0 = pqv[((size_t)(w * 16 + f) * 64 + lane) * 2 + 0];
      uint4 p1 = pqv[((size_t)(w * 16 + f) * 64 + lane) * 2 + 1];
      i32x8 v = {(int)p0.x, (int)p0.y, (int)p0.z, (int)p0.w,
                 (int)p1.x, (int)p1.y, (int)p1.z, (int)p1.w};
      PRv[f] = v;
    }
  }

  if (t < 16) lenl[t] = lens[grp * 16 + t];
  const size_t seqstride = (size_t)Tn * Hn;
  const ushort* myrow = eb + (size_t)(grp * 16 + l15) * seqstride + w * 64 + qg * 16;
  uint* myslot = &BfI[l15 * 132 + (w * 4 + qg) * 4];

  float4 uv0, uv1, uv2, uv3;
  // ---- init: uv = px0sp * e' in the lane's natural (mt*4+r) order ----
  {
    uint4 e0 = *(const uint4*)myrow;
    uint4 e1 = *(const uint4*)(myrow + 8);
    float4 p0 = *(const float4*)(px0sp + w * 64 + qg * 16 + 0);
    float4 p1 = *(const float4*)(px0sp + w * 64 + qg * 16 + 4);
    float4 p2 = *(const float4*)(px0sp + w * 64 + qg * 16 + 8);
    float4 p3 = *(const float4*)(px0sp + w * 64 + qg * 16 + 12);
    uv0.x = p0.x * ubits(e0.x << 16);  uv0.y = p0.y * ubits(e0.x & 0xffff0000u);
    uv0.z = p0.z * ubits(e0.y << 16);  uv0.w = p0.w * ubits(e0.y & 0xffff0000u);
    uv1.x = p1.x * ubits(e0.z << 16);  uv1.y = p1.y * ubits(e0.z & 0xffff0000u);
    uv1.z = p1.z * ubits(e0.w << 16);  uv1.w = p1.w * ubits(e0.w & 0xffff0000u);
    uv2.x = p2.x * ubits(e1.x << 16);  uv2.y = p2.y * ubits(e1.x & 0xffff0000u);
    uv2.z = p2.z * ubits(e1.y << 16);  uv2.w = p2.w * ubits(e1.y & 0xffff0000u);
    uv3.x = p3.x * ubits(e1.z << 16);  uv3.y = p3.y * ubits(e1.z & 0xffff0000u);
    uv3.z = p3.z * ubits(e1.w << 16);  uv3.w = p3.w * ubits(e1.w & 0xffff0000u);
    float m01 = fmaxf(fmaxf(fmaxf(uv0.x, uv0.y), fmaxf(uv0.z, uv0.w)),
                      fmaxf(fmaxf(uv1.x, uv1.y), fmaxf(uv1.z, uv1.w)));
    float m23 = fmaxf(fmaxf(fmaxf(uv2.x, uv2.y), fmaxf(uv2.z, uv2.w)),
                      fmaxf(fmaxf(uv3.x, uv3.y), fmaxf(uv3.z, uv3.w)));
    float mxv = fmaxf(m01, m23);
    mxv = fmaxf(mxv, __shfl_xor(mxv, 16, 64));
    mxv = fmaxf(mxv, __shfl_xor(mxv, 32, 64));
    if (qg == 0) sredM[l15][w] = mxv;
  }
  WG_BARRIER();
  const int t_end = lenl[15];
  const int lenq = lenl[l15];
  float L2acc;
  u64 myf0, myf1;

  // ---- step-0 quantize: pack OWN 16 registers into own slot ----
  {
    float4 g0 = *(const float4*)&sredM[l15][0];
    float4 g1 = *(const float4*)&sredM[l15][4];
    float gm = fmaxf(fmaxf(fmaxf(g0.x, g0.y), fmaxf(g0.z, g0.w)),
                     fmaxf(fmaxf(g1.x, g1.y), fmaxf(g1.z, g1.w)));
    L2acc = __log2f(gm);
    float qs = 448.0f * __builtin_amdgcn_rcpf(gm);
    float v0[8] = {uv0.x, uv0.y, uv0.z, uv0.w, uv1.x, uv1.y, uv1.z, uv1.w};
    float v1[8] = {uv2.x, uv2.y, uv2.z, uv2.w, uv3.x, uv3.y, uv3.z, uv3.w};
    myf0 = pack8fp8(v0, qs);
    myf1 = pack8fp8(v1, qs);
    *(uint4*)myslot = (uint4){(uint)myf0, (uint)(myf0 >> 32), (uint)myf1, (uint)(myf1 >> 32)};
  }

  // ---- emit prefetch: one contiguous 32B per lane ----
  const ushort* epp = myrow + Hn;
  uint4 bpA = *(const uint4*)epp;
  uint4 bpB = *(const uint4*)(epp + 8);
  epp += Hn;

  // ---- recursion: 2 lgkm-only barriers/step ----
  for (int ts = 1; ts < t_end; ts++) {
    WG_BARRIER();  // BAR0: BfI published
    uint4 bqA = *(const uint4*)epp;
    uint4 bqB = *(const uint4*)(epp + 8);
    epp += Hn;

    // MFMA: 4 k-blocks (K=128) x 4 m-tiles; A=P regs, B=alpha LDS
    f32x4 ac0 = {0.f, 0.f, 0.f, 0.f}, ac1 = {0.f, 0.f, 0.f, 0.f};
    f32x4 ac2 = {0.f, 0.f, 0.f, 0.f}, ac3 = {0.f, 0.f, 0.f, 0.f};
#pragma unroll
    for (int kb = 0; kb < 4; kb++) {
      const uint* bp_ = &BfI[l15 * 132 + (kb * 8 + qg * 2) * 4];
      uint4 b0 = *(const uint4*)bp_;
      uint4 b1 = *(const uint4*)(bp_ + 4);
      i32x8 bf = {(int)b0.x, (int)b0.y, (int)b0.z, (int)b0.w,
                  (int)b1.x, (int)b1.y, (int)b1.z, (int)b1.w};
      ac0 = __builtin_amdgcn_mfma_scale_f32_16x16x128_f8f6f4(
          PRv[kb * 4 + 0], bf, ac0, 0, 0, 0, 0x7F7F7F7F, 0, 0x7F7F7F7F);
      ac1 = __builtin_amdgcn_mfma_scale_f32_16x16x128_f8f6f4(
          PRv[kb * 4 + 1], bf, ac1, 0, 0, 0, 0x7F7F7F7F, 0, 0x7F7F7F7F);
      ac2 = __builtin_amdgcn_mfma_scale_f32_16x16x128_f8f6f4(
          PRv[kb * 4 + 2], bf, ac2, 0, 0, 0, 0x7F7F7F7F, 0, 0x7F7F7F7F);
      ac3 = __builtin_amdgcn_mfma_scale_f32_16x16x128_f8f6f4(
          PRv[kb * 4 + 3], bf, ac3, 0, 0, 0, 0x7F7F7F7F, 0, 0x7F7F7F7F);
    }

    // epilogue: u = acc * e' entirely in registers; per-seq max via 2 shfl
    {
      uv0.x = ac0[0] * ubits(bpA.x << 16);  uv0.y = ac0[1] * ubits(bpA.x & 0xffff0000u);
      uv0.z = ac0[2] * ubits(bpA.y << 16);  uv0.w = ac0[3] * ubits(bpA.y & 0xffff0000u);
      uv1.x = ac1[0] * ubits(bpA.z << 16);  uv1.y = ac1[1] * ubits(bpA.z & 0xffff0000u);
      uv1.z = ac1[2] * ubits(bpA.w << 16);  uv1.w = ac1[3] * ubits(bpA.w & 0xffff0000u);
      uv2.x = ac2[0] * ubits(bpB.x << 16);  uv2.y = ac2[1] * ubits(bpB.x & 0xffff0000u);
      uv2.z = ac2[2] * ubits(bpB.y << 16);  uv2.w = ac2[3] * ubits(bpB.y & 0xffff0000u);
      uv3.x = ac3[0] * ubits(bpB.z << 16);  uv3.y = ac3[1] * ubits(bpB.z & 0xffff0000u);
      uv3.z = ac3[2] * ubits(bpB.w << 16);  uv3.w = ac3[3] * ubits(bpB.w & 0xffff0000u);
      float m01 = fmaxf(fmaxf(fmaxf(uv0.x, uv0.y), fmaxf(uv0.z, uv0.w)),
                        fmaxf(fmaxf(uv1.x, uv1.y), fmaxf(uv1.z, uv1.w)));
      float m23 = fmaxf(fmaxf(fmaxf(uv2.x, uv2.y), fmaxf(uv2.z, uv2.w)),
                        fmaxf(fmaxf(uv3.x, uv3.y), fmaxf(uv3.z, uv3.w)));
      float mxv = fmaxf(m01, m23);
      mxv = fmaxf(mxv, __shfl_xor(mxv, 16, 64));
      mxv = fmaxf(mxv, __shfl_xor(mxv, 32, 64));
      if (qg == 0) sredM[l15][w] = mxv;
    }
    WG_BARRIER();  // BAR1: sredM published (only cross-wave dependency)

    // quantize: pack OWN registers, write own slot
    if (ts < lenq) {
      float4 g0 = *(const float4*)&sredM[l15][0];
      float4 g1 = *(const float4*)&sredM[l15][4];
      float gm = fmaxf(fmaxf(fmaxf(g0.x, g0.y), fmaxf(g0.z, g0.w)),
                       fmaxf(fmaxf(g1.x, g1.y), fmaxf(g1.z, g1.w)));
      L2acc += __log2f(gm);
      float qs = 448.0f * __builtin_amdgcn_rcpf(gm);
      float v0[8] = {uv0.x, uv0.y, uv0.z, uv0.w, uv1.x, uv1.y, uv1.z, uv1.w};
      float v1[8] = {uv2.x, uv2.y, uv2.z, uv2.w, uv3.x, uv3.y, uv3.z, uv3.w};
      myf0 = pack8fp8(v0, qs);
      myf1 = pack8fp8(v1, qs);
      *(uint4*)myslot = (uint4){(uint)myf0, (uint)(myf0 >> 32), (uint)myf1, (uint)(myf1 >> 32)};
    }
    bpA = bqA; bpB = bqB;
  }

  // ---- finale ----
  WG_BARRIER();
  {
    float ps = 0.f;
#pragma unroll
    for (int j = 0; j < 8; j++) {
      ps += fp8val((uint)(myf0 >> (8 * j)) & 0xffu);
      ps += fp8val((uint)(myf1 >> (8 * j)) & 0xffu);
    }
    ps += __shfl_xor(ps, 16, 64);
    ps += __shfl_xor(ps, 32, 64);
    if (qg == 0) sredM[l15][w] = ps;  // partial sum over this wave's k-window, seq l15
  }
  // rm sums: wave w handles seqs 2w (lanes 0..31), 2w+1 (lanes 32..63)
  {
    int sq = 2 * w + (lane >> 5), tl = lane & 31;
    const float* rp = rm + (size_t)(grp * 16 + sq) * Tn;
    int ls = lenl[sq];
    float rs = 0.f;
#pragma unroll
    for (int k = 0; k < 16; k++) {
      int idx = tl + 32 * k;
      float v = rp[idx];
      rs += (idx < ls) ? v : 0.f;
    }
#pragma unroll
    for (int o = 1; o < 32; o <<= 1) rs += __shfl_xor(rs, o, 64);
    if ((lane & 31) == 0) rmsL[sq] = rs;
  }
  __syncthreads();
  if (t < 16) {  // wave 0, qg 0, l15 = t: holds L2acc/lenq for seq t
    float4 s0 = *(const float4*)&sredM[t][0];
    float4 s1 = *(const float4*)&sredM[t][4];
    float Ss = (s0.x + s0.y) + (s0.z + s0.w) + (s1.x + s1.y) + (s1.z + s1.w);
    outp[grp * 16 + t] = 0.6931471805599453f * L2acc - (float)lenq * 6.104793232414985f
                         + logf(Ss) + rmsL[t];
  }
}

extern "C" void kernel_launch(void* const* d_in, const int* in_sizes, int n_in,
                              void* d_out, int out_size, void* d_ws, size_t ws_size,
                              hipStream_t stream) {
  const float* seq = (const float*)d_in[0];
  const int* lens = (const int*)d_in[1];
  const float* px = (const float*)d_in[2];
  const float* py = (const float*)d_in[3];
  char* ws = (char*)d_ws;
  ushort* emitb = (ushort*)(ws + 0x0000000);
  float* rm     = (float*)(ws + 0x2000000);
  float* wmat   = (float*)(ws + 0x2020000);
  float* bias   = (float*)(ws + 0x2060000);
  float* cs     = (float*)(ws + 0x2061000);
  float* rcsg   = (float*)(ws + 0x2062000);
  float* px0sp  = (float*)(ws + 0x2063000);
  u64* pq       = (u64*)(ws + 0x2070000);
  float* outp   = (float*)d_out;

  hipLaunchKernelGGL(k_prep, dim3(512), dim3(128), 0, stream, py, wmat, bias);
  hipLaunchKernelGGL(k_cs, dim3(1), dim3(512), 0, stream, px, cs, rcsg, px0sp);
  hipLaunchKernelGGL(k_pq, dim3(32), dim3(256), 0, stream, px, cs, pq);
  hipLaunchKernelGGL(k_emit, dim3(8, 512), dim3(256), 0, stream, seq, wmat, bias, emitb);
  hipLaunchKernelGGL(k_bexp2, dim3(NT), dim3(64), 0, stream, emitb, rm, rcsg);
  hipLaunchKernelGGL(k_rec9, dim3(4), dim3(512), 0, stream, emitb, rm, pq, px0sp, lens, outp);
}

// Round 8
// 662.605 us; speedup vs baseline: 1.9815x; 1.1418x over previous
//
#include <hip/hip_runtime.h>
#include <stdint.h>

#define Hn 512
#define Dn 128
#define Nn 64
#define Tn 512
#define NT (Nn*Tn)   // 32768

typedef unsigned int uint;
typedef unsigned short ushort;
typedef unsigned long long u64;

typedef __attribute__((ext_vector_type(4))) float f32x4;
typedef __attribute__((ext_vector_type(8))) int i32x8;
typedef __attribute__((ext_vector_type(8))) short short8;   // 8 bf16 (4 VGPRs)

// lgkm-only barrier: orders all LDS traffic across the WG without draining vmcnt,
// so global prefetch loads stay in flight across barriers.
#define WG_BARRIER() asm volatile("s_waitcnt lgkmcnt(0)\n\ts_barrier" ::: "memory")

// ---------- ws layout (bytes) ----------
// emitb : 0x0000000  NT*Hn*2  = 32 MB  (exp(emit-rowmax)*rcsg, bf16; cols PERMUTED:
//                    each k_rec lane's 16 values are one contiguous 32B run)
// rm    : 0x2000000  NT*4     = 128 KB
// wmatb : 0x2020000  Hn*Dn*2  = 128 KB (bf16 logit weights)
// bias  : 0x2060000  Hn*4     = 2 KB
// cs    : 0x2061000  Hn*4     (448/colmax of P)
// rcsg  : 0x2062000  Hn*4     (colmax/448)
// px0sp : 0x2063000  Hn*4     (px[0][j]*cs[j], stored PERMUTED like emitb)
// pq    : 0x2070000  256 KB   (P fp8 e4m3, K=128 MFMA A-frags, sigma-permuted byte order)

__device__ inline float bf2f(ushort u) { union { uint i; float f; } v; v.i = uint(u) << 16; return v.f; }
__device__ inline float ubits(uint u) { union { uint i; float f; } v; v.i = u; return v.f; }
__device__ inline ushort f2bf(float f) {
  union { uint i; float f; } v; v.f = f;
  uint u = v.i;
  uint r = (u + 0x7FFFu + ((u >> 16) & 1u)) >> 16;
  return ushort(r);
}
// e4m3fn decode (non-negative only); finale only
__device__ inline float fp8val(uint b) {
  uint e = (b >> 3) & 15u, m = b & 7u;
  return e ? ldexpf((float)(8u + m), (int)e - 10) : ldexpf((float)m, -9);
}
// pack 8 floats to 8 e4m3 bytes; the (position -> k) convention is defined by k_pq's
// sigma gather, applied identically to A and B so HW pairing cancels.
__device__ inline u64 pack8fp8(const float* v, float qs) {
  int lo = 0, hi = 0;
  lo = __builtin_amdgcn_cvt_pk_fp8_f32(v[0] * qs, v[1] * qs, lo, false);
  lo = __builtin_amdgcn_cvt_pk_fp8_f32(v[2] * qs, v[3] * qs, lo, true);
  hi = __builtin_amdgcn_cvt_pk_fp8_f32(v[4] * qs, v[5] * qs, hi, false);
  hi = __builtin_amdgcn_cvt_pk_fp8_f32(v[6] * qs, v[7] * qs, hi, true);
  return (u64)(uint)lo | ((u64)(uint)hi << 32);
}
// col permutation for emitb/px0sp: swap (mt, qg) 2-bit fields within each 64-block
__device__ inline int permcol(int c) {
  return (c & ~63) | ((c & 12) << 2) | ((c & 48) >> 2) | (c & 3);
}

__global__ void k_prep(const float* __restrict__ py, ushort* __restrict__ wmatb,
                       float* __restrict__ bias) {
  int h = blockIdx.x, d = threadIdx.x;
  float p = py[h * Dn + d];
  float lp = logf(p), l1 = log1pf(-p);
  wmatb[h * Dn + d] = f2bf(lp - l1);   // logit, bf16 (A operand is exact 0/1)
  float v = l1;
  for (int o = 1; o < 64; o <<= 1) v += __shfl_xor(v, o, 64);
  __shared__ float s2[2];
  if ((threadIdx.x & 63) == 0) s2[threadIdx.x >> 6] = v;
  __syncthreads();
  if (threadIdx.x == 0) bias[h] = s2[0] + s2[1];
}

// coalesced col-max of P: 1024 threads, col j = t&511, half-row partials in LDS
__global__ __launch_bounds__(1024) void k_cs(const float* __restrict__ px, float* __restrict__ cs,
                                             float* __restrict__ rcsg, float* __restrict__ px0sp) {
  __shared__ float pm[512];
  int t = threadIdx.x;
  int j = t & 511, half = t >> 9;
  float m = 0.f;
  const float* p = px + (size_t)half * 256 * Hn + j;
#pragma unroll 8
  for (int k = 0; k < 256; k++) m = fmaxf(m, p[(size_t)k * Hn]);
  if (half) pm[j] = m;
  __syncthreads();
  if (!half) {
    m = fmaxf(m, pm[j]);
    float c = 448.0f / m;
    cs[j] = c;
    rcsg[j] = m * (1.0f / 448.0f);
    px0sp[permcol(j)] = px[j] * c;
  }
}

// quantize P (col-scaled) into sigma-permuted K=128 A-frag order:
// byte (qa, jj) of block kb <-> k = kb*128 + (qa>>1)*64 + ((jj>>2)&3)*16 + (qa&1)*8 + (jj>>4)*4 + (jj&3)
__global__ __launch_bounds__(256) void k_pq(const float* __restrict__ px, const float* __restrict__ cs,
                                            u64* __restrict__ pq) {
  __shared__ float ksl[512][17];   // 34 KB, padded stride
  int ntg = blockIdx.x;            // global m-tile 0..31
  int t = threadIdx.x;
  for (int i = 0; i < 8; i++) {
    int q = i * 256 + t;           // float4 id over 512x16
    int row = q >> 2, c4 = q & 3;
    float4 v = *(const float4*)(px + (size_t)row * Hn + ntg * 16 + c4 * 4);
    ksl[row][c4 * 4 + 0] = v.x; ksl[row][c4 * 4 + 1] = v.y;
    ksl[row][c4 * 4 + 2] = v.z; ksl[row][c4 * 4 + 3] = v.w;
  }
  __syncthreads();
  int kb = t >> 6, lane = t & 63, qa = lane >> 4, c15 = lane & 15;
  float csv = cs[ntg * 16 + c15];
  int kbase = kb * 128 + (qa >> 1) * 64 + (qa & 1) * 8;
  size_t base = ((size_t)(((ntg >> 2) * 16 + kb * 4 + (ntg & 3)) * 64 + lane)) * 4;
#pragma unroll
  for (int d = 0; d < 4; d++) {
    float vv[8];
#pragma unroll
    for (int b = 0; b < 8; b++) {
      int jj = d * 8 + b;
      int kk = kbase + (((jj >> 2) & 3) << 4) + ((jj >> 4) << 2) + (jj & 3);
      vv[b] = ksl[kk][c15];
    }
    pq[base + d] = pack8fp8(vv, csv);
  }
}

// FUSED emit GEMM (bf16 MFMA) + rowmax + exp + rcsg-scale + permuted eb store + rm store.
// One WG per 64-row strip; full wmat (bf16) + A-tile staged in LDS. Wave w owns rows
// w*16..w*16+15 across ALL 512 cols, so each output row lives in one wave ->
// rowmax is an in-register + 4-round shfl reduce; no extra kernels, no eb re-read.
__global__ __launch_bounds__(256, 1) void k_emit3(
    const float* __restrict__ A, const ushort* __restrict__ wmatb,
    const float* __restrict__ bias, const float* __restrict__ rcsg,
    ushort* __restrict__ eb, float* __restrict__ rm) {
  __shared__ ushort Bs[512][136];   // 139264 B (136: 16B-aligned rows)
  __shared__ ushort As[64][136];    // 17408 B
  __shared__ float biasL[512];      // 2 KB
  __shared__ float rcsL[512];       // 2 KB
  int t = threadIdx.x;
  int r0 = blockIdx.x * 64;
  // stage B: wmatb[512][128] bf16 -> Bs
  for (int i = 0; i < 32; i++) {
    int q = i * 256 + t, row = q >> 4, c = q & 15;
    *(uint4*)&Bs[row][c * 8] = *(const uint4*)(wmatb + row * 128 + c * 8);
  }
  // stage A: 64 rows x 128 f32 -> bf16 (values 0/1: exact)
  for (int i = 0; i < 8; i++) {
    int q = i * 256 + t, row = q >> 5, c4 = q & 31;
    float4 v = *(const float4*)(A + (size_t)(r0 + row) * Dn + c4 * 4);
    ushort4 u4 = {f2bf(v.x), f2bf(v.y), f2bf(v.z), f2bf(v.w)};
    *(ushort4*)&As[row][c4 * 4] = u4;
  }
  biasL[t] = bias[t]; biasL[t + 256] = bias[t + 256];
  rcsL[t] = rcsg[t];  rcsL[t + 256] = rcsg[t + 256];
  __syncthreads();

  const int w = t >> 6, lane = t & 63, l15 = lane & 15, g4 = lane >> 4;
  // A fragments: row = w*16 + l15, k = kt*32 + g4*8 .. +8
  short8 afr[4];
#pragma unroll
  for (int kt = 0; kt < 4; kt++)
    afr[kt] = *(const short8*)&As[w * 16 + l15][kt * 32 + g4 * 8];

  f32x4 acc[32];
#pragma unroll
  for (int nt = 0; nt < 32; nt++) {
    f32x4 a = {0.f, 0.f, 0.f, 0.f};
#pragma unroll
    for (int kt = 0; kt < 4; kt++) {
      short8 bfr = *(const short8*)&Bs[nt * 16 + l15][kt * 32 + g4 * 8];
      a = __builtin_amdgcn_mfma_f32_16x16x32_bf16(afr[kt], bfr, a, 0, 0, 0);
    }
    acc[nt] = a;
  }
  // bias + per-row max (row = w*16 + g4*4 + r, col = nt*16 + l15)
  float mrow[4] = {-1e30f, -1e30f, -1e30f, -1e30f};
#pragma unroll
  for (int nt = 0; nt < 32; nt++) {
    float bv = biasL[nt * 16 + l15];
#pragma unroll
    for (int r = 0; r < 4; r++) {
      float v = acc[nt][r] + bv;
      acc[nt][r] = v;
      mrow[r] = fmaxf(mrow[r], v);
    }
  }
#pragma unroll
  for (int o = 1; o < 16; o <<= 1) {
    mrow[0] = fmaxf(mrow[0], __shfl_xor(mrow[0], o, 64));
    mrow[1] = fmaxf(mrow[1], __shfl_xor(mrow[1], o, 64));
    mrow[2] = fmaxf(mrow[2], __shfl_xor(mrow[2], o, 64));
    mrow[3] = fmaxf(mrow[3], __shfl_xor(mrow[3], o, 64));
  }
  if (l15 == 0) {
#pragma unroll
    for (int r = 0; r < 4; r++) rm[(size_t)(r0 + w * 16 + g4 * 4 + r)] = mrow[r];
  }
  // exp + scale + PERMUTED store
  ushort* ebase = eb + (size_t)(r0 + w * 16 + g4 * 4) * Hn;
#pragma unroll
  for (int nt = 0; nt < 32; nt++) {
    int colp = (nt >> 2) * 64 + (l15 >> 2) * 16 + (nt & 3) * 4 + (l15 & 3);
    float rc = rcsL[nt * 16 + l15];
#pragma unroll
    for (int r = 0; r < 4; r++) {
      float e = __expf(acc[nt][r] - mrow[r]) * rc;
      ebase[(size_t)r * Hn + colp] = f2bf(e);
    }
  }
}

// 4 WGs x 512 threads (8 waves). D = P(A) x alpha(B), sigma-permuted k-order.
// Lane (qg,l15) of wave w owns seq l15, cols {w*64 + mt*16 + qg*4 + r} — and packs
// those SAME 16 registers directly into its 16B BfI slot (no ut array, no transpose).
__global__ __launch_bounds__(512, 2) void k_rec9(
    const ushort* __restrict__ eb, const float* __restrict__ rm,
    const u64* __restrict__ pq, const float* __restrict__ px0sp,
    const int* __restrict__ lens, float* __restrict__ outp) {
  const int grp = blockIdx.x;        // 0..3
  const int t = threadIdx.x;         // 0..511
  const int w = t >> 6;              // wave 0..7
  const int lane = t & 63, qg = lane >> 4, l15 = lane & 15;

  __shared__ uint BfI[16 * 132];     // alpha fp8 image, row pitch 132 words (8.25 KB)
  __shared__ float sredM[16][12];    // per-seq per-wave partial max
  __shared__ float rmsL[16];
  __shared__ int lenl[16];

  // ---- persistent P fragments (A operand): wave w -> m-tiles 4w..4w+3 ----
  i32x8 PRv[16];
  {
    const uint4* pqv = (const uint4*)pq;
#pragma unroll
    for (int f = 0; f < 16; f++) {
      uint4 p0 = pqv[((size_t)(w * 16 + f) * 64 + lane) * 2 + 0];
      uint4 p1 = pqv[((size_t)(w * 16 + f) * 64 + lane) * 2 + 1];
      i32x8 v = {(int)p0.x, (int)p0.y, (int)p0.z, (int)p0.w,
                 (int)p1.x, (int)p1.y, (int)p1.z, (int)p1.w};
      PRv[f] = v;
    }
  }

  if (t < 16) lenl[t] = lens[grp * 16 + t];
  const size_t seqstride = (size_t)Tn * Hn;
  const ushort* myrow = eb + (size_t)(grp * 16 + l15) * seqstride + w * 64 + qg * 16;
  uint* myslot = &BfI[l15 * 132 + (w * 4 + qg) * 4];

  float4 uv0, uv1, uv2, uv3;
  // ---- init: uv = px0sp * e' in the lane's natural (mt*4+r) order ----
  {
    uint4 e0 = *(const uint4*)myrow;
    uint4 e1 = *(const uint4*)(myrow + 8);
    float4 p0 = *(const float4*)(px0sp + w * 64 + qg * 16 + 0);
    float4 p1 = *(const float4*)(px0sp + w * 64 + qg * 16 + 4);
    float4 p2 = *(const float4*)(px0sp + w * 64 + qg * 16 + 8);
    float4 p3 = *(const float4*)(px0sp + w * 64 + qg * 16 + 12);
    uv0.x = p0.x * ubits(e0.x << 16);  uv0.y = p0.y * ubits(e0.x & 0xffff0000u);
    uv0.z = p0.z * ubits(e0.y << 16);  uv0.w = p0.w * ubits(e0.y & 0xffff0000u);
    uv1.x = p1.x * ubits(e0.z << 16);  uv1.y = p1.y * ubits(e0.z & 0xffff0000u);
    uv1.z = p1.z * ubits(e0.w << 16);  uv1.w = p1.w * ubits(e0.w & 0xffff0000u);
    uv2.x = p2.x * ubits(e1.x << 16);  uv2.y = p2.y * ubits(e1.x & 0xffff0000u);
    uv2.z = p2.z * ubits(e1.y << 16);  uv2.w = p2.w * ubits(e1.y & 0xffff0000u);
    uv3.x = p3.x * ubits(e1.z << 16);  uv3.y = p3.y * ubits(e1.z & 0xffff0000u);
    uv3.z = p3.z * ubits(e1.w << 16);  uv3.w = p3.w * ubits(e1.w & 0xffff0000u);
    float m01 = fmaxf(fmaxf(fmaxf(uv0.x, uv0.y), fmaxf(uv0.z, uv0.w)),
                      fmaxf(fmaxf(uv1.x, uv1.y), fmaxf(uv1.z, uv1.w)));
    float m23 = fmaxf(fmaxf(fmaxf(uv2.x, uv2.y), fmaxf(uv2.z, uv2.w)),
                      fmaxf(fmaxf(uv3.x, uv3.y), fmaxf(uv3.z, uv3.w)));
    float mxv = fmaxf(m01, m23);
    mxv = fmaxf(mxv, __shfl_xor(mxv, 16, 64));
    mxv = fmaxf(mxv, __shfl_xor(mxv, 32, 64));
    if (qg == 0) sredM[l15][w] = mxv;
  }
  WG_BARRIER();
  const int t_end = lenl[15];
  const int lenq = lenl[l15];
  float L2acc;
  u64 myf0, myf1;

  // ---- step-0 quantize: pack OWN 16 registers into own slot ----
  {
    float4 g0 = *(const float4*)&sredM[l15][0];
    float4 g1 = *(const float4*)&sredM[l15][4];
    float gm = fmaxf(fmaxf(fmaxf(g0.x, g0.y), fmaxf(g0.z, g0.w)),
                     fmaxf(fmaxf(g1.x, g1.y), fmaxf(g1.z, g1.w)));
    L2acc = __log2f(gm);
    float qs = 448.0f * __builtin_amdgcn_rcpf(gm);
    float v0[8] = {uv0.x, uv0.y, uv0.z, uv0.w, uv1.x, uv1.y, uv1.z, uv1.w};
    float v1[8] = {uv2.x, uv2.y, uv2.z, uv2.w, uv3.x, uv3.y, uv3.z, uv3.w};
    myf0 = pack8fp8(v0, qs);
    myf1 = pack8fp8(v1, qs);
    *(uint4*)myslot = (uint4){(uint)myf0, (uint)(myf0 >> 32), (uint)myf1, (uint)(myf1 >> 32)};
  }

  // ---- emit prefetch: one contiguous 32B per lane ----
  const ushort* epp = myrow + Hn;
  uint4 bpA = *(const uint4*)epp;
  uint4 bpB = *(const uint4*)(epp + 8);
  epp += Hn;

  // ---- recursion: 2 lgkm-only barriers/step ----
  for (int ts = 1; ts < t_end; ts++) {
    WG_BARRIER();  // BAR0: BfI published
    uint4 bqA = *(const uint4*)epp;
    uint4 bqB = *(const uint4*)(epp + 8);
    epp += Hn;

    // MFMA: 4 k-blocks (K=128) x 4 m-tiles; A=P regs, B=alpha LDS
    f32x4 ac0 = {0.f, 0.f, 0.f, 0.f}, ac1 = {0.f, 0.f, 0.f, 0.f};
    f32x4 ac2 = {0.f, 0.f, 0.f, 0.f}, ac3 = {0.f, 0.f, 0.f, 0.f};
#pragma unroll
    for (int kb = 0; kb < 4; kb++) {
      const uint* bp_ = &BfI[l15 * 132 + (kb * 8 + qg * 2) * 4];
      uint4 b0 = *(const uint4*)bp_;
      uint4 b1 = *(const uint4*)(bp_ + 4);
      i32x8 bf = {(int)b0.x, (int)b0.y, (int)b0.z, (int)b0.w,
                  (int)b1.x, (int)b1.y, (int)b1.z, (int)b1.w};
      ac0 = __builtin_amdgcn_mfma_scale_f32_16x16x128_f8f6f4(
          PRv[kb * 4 + 0], bf, ac0, 0, 0, 0, 0x7F7F7F7F, 0, 0x7F7F7F7F);
      ac1 = __builtin_amdgcn_mfma_scale_f32_16x16x128_f8f6f4(
          PRv[kb * 4 + 1], bf, ac1, 0, 0, 0, 0x7F7F7F7F, 0, 0x7F7F7F7F);
      ac2 = __builtin_amdgcn_mfma_scale_f32_16x16x128_f8f6f4(
          PRv[kb * 4 + 2], bf, ac2, 0, 0, 0, 0x7F7F7F7F, 0, 0x7F7F7F7F);
      ac3 = __builtin_amdgcn_mfma_scale_f32_16x16x128_f8f6f4(
          PRv[kb * 4 + 3], bf, ac3, 0, 0, 0, 0x7F7F7F7F, 0, 0x7F7F7F7F);
    }

    // epilogue: u = acc * e' entirely in registers; per-seq max via 2 shfl
    {
      uv0.x = ac0[0] * ubits(bpA.x << 16);  uv0.y = ac0[1] * ubits(bpA.x & 0xffff0000u);
      uv0.z = ac0[2] * ubits(bpA.y << 16);  uv0.w = ac0[3] * ubits(bpA.y & 0xffff0000u);
      uv1.x = ac1[0] * ubits(bpA.z << 16);  uv1.y = ac1[1] * ubits(bpA.z & 0xffff0000u);
      uv1.z = ac1[2] * ubits(bpA.w << 16);  uv1.w = ac1[3] * ubits(bpA.w & 0xffff0000u);
      uv2.x = ac2[0] * ubits(bpB.x << 16);  uv2.y = ac2[1] * ubits(bpB.x & 0xffff0000u);
      uv2.z = ac2[2] * ubits(bpB.y << 16);  uv2.w = ac2[3] * ubits(bpB.y & 0xffff0000u);
      uv3.x = ac3[0] * ubits(bpB.z << 16);  uv3.y = ac3[1] * ubits(bpB.z & 0xffff0000u);
      uv3.z = ac3[2] * ubits(bpB.w << 16);  uv3.w = ac3[3] * ubits(bpB.w & 0xffff0000u);
      float m01 = fmaxf(fmaxf(fmaxf(uv0.x, uv0.y), fmaxf(uv0.z, uv0.w)),
                        fmaxf(fmaxf(uv1.x, uv1.y), fmaxf(uv1.z, uv1.w)));
      float m23 = fmaxf(fmaxf(fmaxf(uv2.x, uv2.y), fmaxf(uv2.z, uv2.w)),
                        fmaxf(fmaxf(uv3.x, uv3.y), fmaxf(uv3.z, uv3.w)));
      float mxv = fmaxf(m01, m23);
      mxv = fmaxf(mxv, __shfl_xor(mxv, 16, 64));
      mxv = fmaxf(mxv, __shfl_xor(mxv, 32, 64));
      if (qg == 0) sredM[l15][w] = mxv;
    }
    WG_BARRIER();  // BAR1: sredM published (only cross-wave dependency)

    // quantize: pack OWN registers, write own slot
    if (ts < lenq) {
      float4 g0 = *(const float4*)&sredM[l15][0];
      float4 g1 = *(const float4*)&sredM[l15][4];
      float gm = fmaxf(fmaxf(fmaxf(g0.x, g0.y), fmaxf(g0.z, g0.w)),
                       fmaxf(fmaxf(g1.x, g1.y), fmaxf(g1.z, g1.w)));
      L2acc += __log2f(gm);
      float qs = 448.0f * __builtin_amdgcn_rcpf(gm);
      float v0[8] = {uv0.x, uv0.y, uv0.z, uv0.w, uv1.x, uv1.y, uv1.z, uv1.w};
      float v1[8] = {uv2.x, uv2.y, uv2.z, uv2.w, uv3.x, uv3.y, uv3.z, uv3.w};
      myf0 = pack8fp8(v0, qs);
      myf1 = pack8fp8(v1, qs);
      *(uint4*)myslot = (uint4){(uint)myf0, (uint)(myf0 >> 32), (uint)myf1, (uint)(myf1 >> 32)};
    }
    bpA = bqA; bpB = bqB;
  }

  // ---- finale ----
  WG_BARRIER();
  {
    float ps = 0.f;
#pragma unroll
    for (int j = 0; j < 8; j++) {
      ps += fp8val((uint)(myf0 >> (8 * j)) & 0xffu);
      ps += fp8val((uint)(myf1 >> (8 * j)) & 0xffu);
    }
    ps += __shfl_xor(ps, 16, 64);
    ps += __shfl_xor(ps, 32, 64);
    if (qg == 0) sredM[l15][w] = ps;  // partial sum over this wave's k-window, seq l15
  }
  // rm sums: wave w handles seqs 2w (lanes 0..31), 2w+1 (lanes 32..63)
  {
    int sq = 2 * w + (lane >> 5), tl = lane & 31;
    const float* rp = rm + (size_t)(grp * 16 + sq) * Tn;
    int ls = lenl[sq];
    float rs = 0.f;
#pragma unroll
    for (int k = 0; k < 16; k++) {
      int idx = tl + 32 * k;
      float v = rp[idx];
      rs += (idx < ls) ? v : 0.f;
    }
#pragma unroll
    for (int o = 1; o < 32; o <<= 1) rs += __shfl_xor(rs, o, 64);
    if ((lane & 31) == 0) rmsL[sq] = rs;
  }
  __syncthreads();
  if (t < 16) {  // wave 0, qg 0, l15 = t: holds L2acc/lenq for seq t
    float4 s0 = *(const float4*)&sredM[t][0];
    float4 s1 = *(const float4*)&sredM[t][4];
    float Ss = (s0.x + s0.y) + (s0.z + s0.w) + (s1.x + s1.y) + (s1.z + s1.w);
    outp[grp * 16 + t] = 0.6931471805599453f * L2acc - (float)lenq * 6.104793232414985f
                         + logf(Ss) + rmsL[t];
  }
}

extern "C" void kernel_launch(void* const* d_in, const int* in_sizes, int n_in,
                              void* d_out, int out_size, void* d_ws, size_t ws_size,
                              hipStream_t stream) {
  const float* seq = (const float*)d_in[0];
  const int* lens = (const int*)d_in[1];
  const float* px = (const float*)d_in[2];
  const float* py = (const float*)d_in[3];
  char* ws = (char*)d_ws;
  ushort* emitb = (ushort*)(ws + 0x0000000);
  float* rm     = (float*)(ws + 0x2000000);
  ushort* wmatb = (ushort*)(ws + 0x2020000);
  float* bias   = (float*)(ws + 0x2060000);
  float* cs     = (float*)(ws + 0x2061000);
  float* rcsg   = (float*)(ws + 0x2062000);
  float* px0sp  = (float*)(ws + 0x2063000);
  u64* pq       = (u64*)(ws + 0x2070000);
  float* outp   = (float*)d_out;

  hipLaunchKernelGGL(k_prep, dim3(512), dim3(128), 0, stream, py, wmatb, bias);
  hipLaunchKernelGGL(k_cs, dim3(1), dim3(1024), 0, stream, px, cs, rcsg, px0sp);
  hipLaunchKernelGGL(k_pq, dim3(32), dim3(256), 0, stream, px, cs, pq);
  hipLaunchKernelGGL(k_emit3, dim3(NT / 64), dim3(256), 0, stream, seq, wmatb, bias, rcsg, emitb, rm);
  hipLaunchKernelGGL(k_rec9, dim3(4), dim3(512), 0, stream, emitb, rm, pq, px0sp, lens, outp);
}

// Round 9
// 606.508 us; speedup vs baseline: 2.1648x; 1.0925x over previous
//
#include <hip/hip_runtime.h>
#include <stdint.h>

#define Hn 512
#define Dn 128
#define Nn 64
#define Tn 512
#define NT (Nn*Tn)   // 32768

typedef unsigned int uint;
typedef unsigned short ushort;
typedef unsigned long long u64;

typedef __attribute__((ext_vector_type(4))) float f32x4;
typedef __attribute__((ext_vector_type(8))) int i32x8;
typedef __attribute__((ext_vector_type(8))) short short8;   // 8 bf16 (4 VGPRs)

// lgkm-only barrier: orders all LDS traffic across the WG without draining vmcnt,
// so global prefetch loads stay in flight across barriers.
#define WG_BARRIER() asm volatile("s_waitcnt lgkmcnt(0)\n\ts_barrier" ::: "memory")

// ---------- ws layout (bytes) ----------
// emitb : 0x0000000  NT*Hn*2  = 32 MB  (exp(emit-rowmax)*rcsg, bf16; cols PERMUTED:
//                    each k_rec lane's 16 values are one contiguous 32B run)
// rm    : 0x2000000  NT*4     = 128 KB
// wmatb : 0x2020000  Hn*Dn*2  = 128 KB (bf16 logit weights)
// bias  : 0x2060000  Hn*4     = 2 KB
// (cs   : 0x2061000  unused now - colmax lives inside k_pq)
// rcsg  : 0x2062000  Hn*4     (colmax/448)
// px0sp : 0x2063000  Hn*4     (px[0][j]*cs[j], stored PERMUTED like emitb)
// pq    : 0x2070000  256 KB   (P fp8 e4m3, K=128 MFMA A-frags, sigma-permuted byte order)

__device__ inline float bf2f(ushort u) { union { uint i; float f; } v; v.i = uint(u) << 16; return v.f; }
__device__ inline float ubits(uint u) { union { uint i; float f; } v; v.i = u; return v.f; }
__device__ inline ushort f2bf(float f) {
  union { uint i; float f; } v; v.f = f;
  uint u = v.i;
  uint r = (u + 0x7FFFu + ((u >> 16) & 1u)) >> 16;
  return ushort(r);
}
// e4m3fn decode (non-negative only); finale only
__device__ inline float fp8val(uint b) {
  uint e = (b >> 3) & 15u, m = b & 7u;
  return e ? ldexpf((float)(8u + m), (int)e - 10) : ldexpf((float)m, -9);
}
// pack 8 floats to 8 e4m3 bytes; the (position -> k) convention is defined by k_pq's
// sigma gather, applied identically to A and B so HW pairing cancels.
__device__ inline u64 pack8fp8(const float* v, float qs) {
  int lo = 0, hi = 0;
  lo = __builtin_amdgcn_cvt_pk_fp8_f32(v[0] * qs, v[1] * qs, lo, false);
  lo = __builtin_amdgcn_cvt_pk_fp8_f32(v[2] * qs, v[3] * qs, lo, true);
  hi = __builtin_amdgcn_cvt_pk_fp8_f32(v[4] * qs, v[5] * qs, hi, false);
  hi = __builtin_amdgcn_cvt_pk_fp8_f32(v[6] * qs, v[7] * qs, hi, true);
  return (u64)(uint)lo | ((u64)(uint)hi << 32);
}
// col permutation for emitb/px0sp: swap (mt, qg) 2-bit fields within each 64-block
__device__ inline int permcol(int c) {
  return (c & ~63) | ((c & 12) << 2) | ((c & 48) >> 2) | (c & 3);
}

__global__ void k_prep(const float* __restrict__ py, ushort* __restrict__ wmatb,
                       float* __restrict__ bias) {
  int h = blockIdx.x, d = threadIdx.x;
  float p = py[h * Dn + d];
  float lp = logf(p), l1 = log1pf(-p);
  wmatb[h * Dn + d] = f2bf(lp - l1);   // logit, bf16 (A operand is exact 0/1)
  float v = l1;
  for (int o = 1; o < 64; o <<= 1) v += __shfl_xor(v, o, 64);
  __shared__ float s2[2];
  if ((threadIdx.x & 63) == 0) s2[threadIdx.x >> 6] = v;
  __syncthreads();
  if (threadIdx.x == 0) bias[h] = s2[0] + s2[1];
}

// FUSED colmax + quantize of P into sigma-permuted K=128 A-frag order:
// byte (qa, jj) of block kb <-> k = kb*128 + (qa>>1)*64 + ((jj>>2)&3)*16 + (qa&1)*8 + (jj>>4)*4 + (jj&3)
__global__ __launch_bounds__(256) void k_pq(const float* __restrict__ px,
                                            float* __restrict__ rcsg, float* __restrict__ px0sp,
                                            u64* __restrict__ pq) {
  __shared__ float ksl[512][17];   // 34 KB, padded stride
  __shared__ float pm[16][17];
  __shared__ float csL[16];
  int ntg = blockIdx.x;            // global m-tile 0..31
  int t = threadIdx.x;
  for (int i = 0; i < 8; i++) {
    int q = i * 256 + t;           // float4 id over 512x16
    int row = q >> 2, c4 = q & 3;
    float4 v = *(const float4*)(px + (size_t)row * Hn + ntg * 16 + c4 * 4);
    ksl[row][c4 * 4 + 0] = v.x; ksl[row][c4 * 4 + 1] = v.y;
    ksl[row][c4 * 4 + 2] = v.z; ksl[row][c4 * 4 + 3] = v.w;
  }
  __syncthreads();
  // col-max of the staged 512x16 slice
  {
    int c = t & 15, ch = t >> 4;   // 16 chunks x 32 rows
    float m = 0.f;
#pragma unroll
    for (int r = 0; r < 32; r++) m = fmaxf(m, ksl[ch * 32 + r][c]);
    pm[ch][c] = m;
  }
  __syncthreads();
  if (t < 16) {
    float m = pm[0][t];
#pragma unroll
    for (int i = 1; i < 16; i++) m = fmaxf(m, pm[i][t]);
    float c = 448.0f / m;
    csL[t] = c;
    rcsg[ntg * 16 + t] = m * (1.0f / 448.0f);
    px0sp[permcol(ntg * 16 + t)] = px[ntg * 16 + t] * c;   // row 0 of px, pre-scaled
  }
  __syncthreads();
  int kb = t >> 6, lane = t & 63, qa = lane >> 4, c15 = lane & 15;
  float csv = csL[c15];
  int kbase = kb * 128 + (qa >> 1) * 64 + (qa & 1) * 8;
  size_t base = ((size_t)(((ntg >> 2) * 16 + kb * 4 + (ntg & 3)) * 64 + lane)) * 4;
#pragma unroll
  for (int d = 0; d < 4; d++) {
    float vv[8];
#pragma unroll
    for (int b = 0; b < 8; b++) {
      int jj = d * 8 + b;
      int kk = kbase + (((jj >> 2) & 3) << 4) + ((jj >> 4) << 2) + (jj & 3);
      vv[b] = ksl[kk][c15];
    }
    pq[base + d] = pack8fp8(vv, csv);
  }
}

// FUSED emit GEMM (bf16 MFMA) + rowmax + exp + rcsg-scale + permuted eb store + rm store.
// B staged in 4 chunks of 128 rows -> 56 KB LDS -> 2 WGs/CU (was 160 KB, 1 WG/CU).
__global__ __launch_bounds__(256, 2) void k_emit3(
    const float* __restrict__ A, const ushort* __restrict__ wmatb,
    const float* __restrict__ bias, const float* __restrict__ rcsg,
    ushort* __restrict__ eb, float* __restrict__ rm) {
  __shared__ ushort Bs[128][136];   // 34816 B (one 128-row chunk of wmatb)
  __shared__ ushort As[64][136];    // 17408 B
  __shared__ float biasL[512];      // 2 KB
  __shared__ float rcsL[512];       // 2 KB
  int t = threadIdx.x;
  int r0 = blockIdx.x * 64;
  // stage A: 64 rows x 128 f32 -> bf16 (values 0/1: exact)
  for (int i = 0; i < 8; i++) {
    int q = i * 256 + t, row = q >> 5, c4 = q & 31;
    float4 v = *(const float4*)(A + (size_t)(r0 + row) * Dn + c4 * 4);
    ushort4 u4 = {f2bf(v.x), f2bf(v.y), f2bf(v.z), f2bf(v.w)};
    *(ushort4*)&As[row][c4 * 4] = u4;
  }
  biasL[t] = bias[t]; biasL[t + 256] = bias[t + 256];
  rcsL[t] = rcsg[t];  rcsL[t + 256] = rcsg[t + 256];
  __syncthreads();

  const int w = t >> 6, lane = t & 63, l15 = lane & 15, g4 = lane >> 4;
  // A fragments: row = w*16 + l15, k = kt*32 + g4*8 .. +8
  short8 afr[4];
#pragma unroll
  for (int kt = 0; kt < 4; kt++)
    afr[kt] = *(const short8*)&As[w * 16 + l15][kt * 32 + g4 * 8];

  f32x4 acc[32];
  for (int cc = 0; cc < 4; cc++) {
    __syncthreads();   // Bs free for overwrite
    for (int i = 0; i < 8; i++) {
      int q = i * 256 + t, row = q >> 4, c = q & 15;
      *(uint4*)&Bs[row][c * 8] = *(const uint4*)(wmatb + (cc * 128 + row) * 128 + c * 8);
    }
    __syncthreads();   // Bs staged
#pragma unroll
    for (int n8 = 0; n8 < 8; n8++) {
      int nt = cc * 8 + n8;
      f32x4 a = {0.f, 0.f, 0.f, 0.f};
#pragma unroll
      for (int kt = 0; kt < 4; kt++) {
        short8 bfr = *(const short8*)&Bs[n8 * 16 + l15][kt * 32 + g4 * 8];
        a = __builtin_amdgcn_mfma_f32_16x16x32_bf16(afr[kt], bfr, a, 0, 0, 0);
      }
      acc[nt] = a;
    }
  }
  // bias + per-row max (row = w*16 + g4*4 + r, col = nt*16 + l15)
  float mrow[4] = {-1e30f, -1e30f, -1e30f, -1e30f};
#pragma unroll
  for (int nt = 0; nt < 32; nt++) {
    float bv = biasL[nt * 16 + l15];
#pragma unroll
    for (int r = 0; r < 4; r++) {
      float v = acc[nt][r] + bv;
      acc[nt][r] = v;
      mrow[r] = fmaxf(mrow[r], v);
    }
  }
#pragma unroll
  for (int o = 1; o < 16; o <<= 1) {
    mrow[0] = fmaxf(mrow[0], __shfl_xor(mrow[0], o, 64));
    mrow[1] = fmaxf(mrow[1], __shfl_xor(mrow[1], o, 64));
    mrow[2] = fmaxf(mrow[2], __shfl_xor(mrow[2], o, 64));
    mrow[3] = fmaxf(mrow[3], __shfl_xor(mrow[3], o, 64));
  }
  if (l15 == 0) {
#pragma unroll
    for (int r = 0; r < 4; r++) rm[(size_t)(r0 + w * 16 + g4 * 4 + r)] = mrow[r];
  }
  // exp + scale + PERMUTED store
  ushort* ebase = eb + (size_t)(r0 + w * 16 + g4 * 4) * Hn;
#pragma unroll
  for (int nt = 0; nt < 32; nt++) {
    int colp = (nt >> 2) * 64 + (l15 >> 2) * 16 + (nt & 3) * 4 + (l15 & 3);
    float rc = rcsL[nt * 16 + l15];
#pragma unroll
    for (int r = 0; r < 4; r++) {
      float e = __expf(acc[nt][r] - mrow[r]) * rc;
      ebase[(size_t)r * Hn + colp] = f2bf(e);
    }
  }
}

// 4 WGs x 512 threads (8 waves). D = P(A) x alpha(B), sigma-permuted k-order.
// Lane (qg,l15) of wave w owns seq l15, cols {w*64 + mt*16 + qg*4 + r} — and packs
// those SAME 16 registers directly into its 16B BfI slot (no ut array, no transpose).
// BfI layout [slot16B][seq]: both the quantize WRITE (wave w covers bytes
// (w*4+qg)*256 + 16*l15, contiguous 1 KB/wave) and the MFMA READ (per kb:
// (kb*8+2qg)*256 + 16*l15, contiguous 2 KB/wave) are canonical conflict-free patterns.
__global__ __launch_bounds__(512, 2) void k_rec9(
    const ushort* __restrict__ eb, const float* __restrict__ rm,
    const u64* __restrict__ pq, const float* __restrict__ px0sp,
    const int* __restrict__ lens, float* __restrict__ outp) {
  const int grp = blockIdx.x;        // 0..3
  const int t = threadIdx.x;         // 0..511
  const int w = t >> 6;              // wave 0..7
  const int lane = t & 63, qg = lane >> 4, l15 = lane & 15;

  __shared__ uint4 BfI[32][16];      // alpha fp8 image [16B-slot][seq] (8 KB)
  __shared__ float sredM[16][12];    // per-seq per-wave partial max
  __shared__ float rmsL[16];
  __shared__ int lenl[16];

  // ---- persistent P fragments (A operand): wave w -> m-tiles 4w..4w+3 ----
  i32x8 PRv[16];
  {
    const uint4* pqv = (const uint4*)pq;
#pragma unroll
    for (int f = 0; f < 16; f++) {
      uint4 p0 = pqv[((size_t)(w * 16 + f) * 64 + lane) * 2 + 0];
      uint4 p1 = pqv[((size_t)(w * 16 + f) * 64 + lane) * 2 + 1];
      i32x8 v = {(int)p0.x, (int)p0.y, (int)p0.z, (int)p0.w,
                 (int)p1.x, (int)p1.y, (int)p1.z, (int)p1.w};
      PRv[f] = v;
    }
  }

  if (t < 16) lenl[t] = lens[grp * 16 + t];
  const size_t seqstride = (size_t)Tn * Hn;
  const ushort* myrow = eb + (size_t)(grp * 16 + l15) * seqstride + w * 64 + qg * 16;
  uint4* myslot = &BfI[w * 4 + qg][l15];

  float4 uv0, uv1, uv2, uv3;
  // ---- init: uv = px0sp * e' in the lane's natural (mt*4+r) order ----
  {
    uint4 e0 = *(const uint4*)myrow;
    uint4 e1 = *(const uint4*)(myrow + 8);
    float4 p0 = *(const float4*)(px0sp + w * 64 + qg * 16 + 0);
    float4 p1 = *(const float4*)(px0sp + w * 64 + qg * 16 + 4);
    float4 p2 = *(const float4*)(px0sp + w * 64 + qg * 16 + 8);
    float4 p3 = *(const float4*)(px0sp + w * 64 + qg * 16 + 12);
    uv0.x = p0.x * ubits(e0.x << 16);  uv0.y = p0.y * ubits(e0.x & 0xffff0000u);
    uv0.z = p0.z * ubits(e0.y << 16);  uv0.w = p0.w * ubits(e0.y & 0xffff0000u);
    uv1.x = p1.x * ubits(e0.z << 16);  uv1.y = p1.y * ubits(e0.z & 0xffff0000u);
    uv1.z = p1.z * ubits(e0.w << 16);  uv1.w = p1.w * ubits(e0.w & 0xffff0000u);
    uv2.x = p2.x * ubits(e1.x << 16);  uv2.y = p2.y * ubits(e1.x & 0xffff0000u);
    uv2.z = p2.z * ubits(e1.y << 16);  uv2.w = p2.w * ubits(e1.y & 0xffff0000u);
    uv3.x = p3.x * ubits(e1.z << 16);  uv3.y = p3.y * ubits(e1.z & 0xffff0000u);
    uv3.z = p3.z * ubits(e1.w << 16);  uv3.w = p3.w * ubits(e1.w & 0xffff0000u);
    float m01 = fmaxf(fmaxf(fmaxf(uv0.x, uv0.y), fmaxf(uv0.z, uv0.w)),
                      fmaxf(fmaxf(uv1.x, uv1.y), fmaxf(uv1.z, uv1.w)));
    float m23 = fmaxf(fmaxf(fmaxf(uv2.x, uv2.y), fmaxf(uv2.z, uv2.w)),
                      fmaxf(fmaxf(uv3.x, uv3.y), fmaxf(uv3.z, uv3.w)));
    float mxv = fmaxf(m01, m23);
    mxv = fmaxf(mxv, __shfl_xor(mxv, 16, 64));
    mxv = fmaxf(mxv, __shfl_xor(mxv, 32, 64));
    if (qg == 0) sredM[l15][w] = mxv;
  }
  WG_BARRIER();
  const int t_end = lenl[15];
  const int lenq = lenl[l15];
  float L2acc;
  u64 myf0, myf1;

  // ---- step-0 quantize: pack OWN 16 registers into own slot ----
  {
    float4 g0 = *(const float4*)&sredM[l15][0];
    float4 g1 = *(const float4*)&sredM[l15][4];
    float gm = fmaxf(fmaxf(fmaxf(g0.x, g0.y), fmaxf(g0.z, g0.w)),
                     fmaxf(fmaxf(g1.x, g1.y), fmaxf(g1.z, g1.w)));
    L2acc = __log2f(gm);
    float qs = 448.0f * __builtin_amdgcn_rcpf(gm);
    float v0[8] = {uv0.x, uv0.y, uv0.z, uv0.w, uv1.x, uv1.y, uv1.z, uv1.w};
    float v1[8] = {uv2.x, uv2.y, uv2.z, uv2.w, uv3.x, uv3.y, uv3.z, uv3.w};
    myf0 = pack8fp8(v0, qs);
    myf1 = pack8fp8(v1, qs);
    *myslot = (uint4){(uint)myf0, (uint)(myf0 >> 32), (uint)myf1, (uint)(myf1 >> 32)};
  }

  // ---- emit prefetch: one contiguous 32B per lane ----
  const ushort* epp = myrow + Hn;
  uint4 bpA = *(const uint4*)epp;
  uint4 bpB = *(const uint4*)(epp + 8);
  epp += Hn;

  // ---- recursion: 2 lgkm-only barriers/step ----
  for (int ts = 1; ts < t_end; ts++) {
    WG_BARRIER();  // BAR0: BfI published

    // MFMA: 4 k-blocks (K=128) x 4 m-tiles; A=P regs, B=alpha LDS (conflict-free reads)
    f32x4 ac0 = {0.f, 0.f, 0.f, 0.f}, ac1 = {0.f, 0.f, 0.f, 0.f};
    f32x4 ac2 = {0.f, 0.f, 0.f, 0.f}, ac3 = {0.f, 0.f, 0.f, 0.f};
    __builtin_amdgcn_s_setprio(1);
#pragma unroll
    for (int kb = 0; kb < 4; kb++) {
      uint4 b0 = BfI[kb * 8 + qg * 2 + 0][l15];
      uint4 b1 = BfI[kb * 8 + qg * 2 + 1][l15];
      i32x8 bf = {(int)b0.x, (int)b0.y, (int)b0.z, (int)b0.w,
                  (int)b1.x, (int)b1.y, (int)b1.z, (int)b1.w};
      ac0 = __builtin_amdgcn_mfma_scale_f32_16x16x128_f8f6f4(
          PRv[kb * 4 + 0], bf, ac0, 0, 0, 0, 0x7F7F7F7F, 0, 0x7F7F7F7F);
      ac1 = __builtin_amdgcn_mfma_scale_f32_16x16x128_f8f6f4(
          PRv[kb * 4 + 1], bf, ac1, 0, 0, 0, 0x7F7F7F7F, 0, 0x7F7F7F7F);
      ac2 = __builtin_amdgcn_mfma_scale_f32_16x16x128_f8f6f4(
          PRv[kb * 4 + 2], bf, ac2, 0, 0, 0, 0x7F7F7F7F, 0, 0x7F7F7F7F);
      ac3 = __builtin_amdgcn_mfma_scale_f32_16x16x128_f8f6f4(
          PRv[kb * 4 + 3], bf, ac3, 0, 0, 0, 0x7F7F7F7F, 0, 0x7F7F7F7F);
    }
    __builtin_amdgcn_s_setprio(0);

    // prefetch emit(ts+1) AFTER the MFMA issue (off the pre-MFMA critical path);
    // lands during epilogue+quantize+barrier of this step, consumed next iteration.
    uint4 bqA = *(const uint4*)epp;
    uint4 bqB = *(const uint4*)(epp + 8);
    epp += Hn;

    // epilogue: u = acc * e' entirely in registers; per-seq max via 2 shfl
    {
      uv0.x = ac0[0] * ubits(bpA.x << 16);  uv0.y = ac0[1] * ubits(bpA.x & 0xffff0000u);
      uv0.z = ac0[2] * ubits(bpA.y << 16);  uv0.w = ac0[3] * ubits(bpA.y & 0xffff0000u);
      uv1.x = ac1[0] * ubits(bpA.z << 16);  uv1.y = ac1[1] * ubits(bpA.z & 0xffff0000u);
      uv1.z = ac1[2] * ubits(bpA.w << 16);  uv1.w = ac1[3] * ubits(bpA.w & 0xffff0000u);
      uv2.x = ac2[0] * ubits(bpB.x << 16);  uv2.y = ac2[1] * ubits(bpB.x & 0xffff0000u);
      uv2.z = ac2[2] * ubits(bpB.y << 16);  uv2.w = ac2[3] * ubits(bpB.y & 0xffff0000u);
      uv3.x = ac3[0] * ubits(bpB.z << 16);  uv3.y = ac3[1] * ubits(bpB.z & 0xffff0000u);
      uv3.z = ac3[2] * ubits(bpB.w << 16);  uv3.w = ac3[3] * ubits(bpB.w & 0xffff0000u);
      float m01 = fmaxf(fmaxf(fmaxf(uv0.x, uv0.y), fmaxf(uv0.z, uv0.w)),
                        fmaxf(fmaxf(uv1.x, uv1.y), fmaxf(uv1.z, uv1.w)));
      float m23 = fmaxf(fmaxf(fmaxf(uv2.x, uv2.y), fmaxf(uv2.z, uv2.w)),
                        fmaxf(fmaxf(uv3.x, uv3.y), fmaxf(uv3.z, uv3.w)));
      float mxv = fmaxf(m01, m23);
      mxv = fmaxf(mxv, __shfl_xor(mxv, 16, 64));
      mxv = fmaxf(mxv, __shfl_xor(mxv, 32, 64));
      if (qg == 0) sredM[l15][w] = mxv;
    }
    WG_BARRIER();  // BAR1: sredM published (only cross-wave dependency)

    // quantize: pack OWN registers, write own slot (conflict-free contiguous write)
    if (ts < lenq) {
      float4 g0 = *(const float4*)&sredM[l15][0];
      float4 g1 = *(const float4*)&sredM[l15][4];
      float gm = fmaxf(fmaxf(fmaxf(g0.x, g0.y), fmaxf(g0.z, g0.w)),
                       fmaxf(fmaxf(g1.x, g1.y), fmaxf(g1.z, g1.w)));
      L2acc += __log2f(gm);
      float qs = 448.0f * __builtin_amdgcn_rcpf(gm);
      float v0[8] = {uv0.x, uv0.y, uv0.z, uv0.w, uv1.x, uv1.y, uv1.z, uv1.w};
      float v1[8] = {uv2.x, uv2.y, uv2.z, uv2.w, uv3.x, uv3.y, uv3.z, uv3.w};
      myf0 = pack8fp8(v0, qs);
      myf1 = pack8fp8(v1, qs);
      *myslot = (uint4){(uint)myf0, (uint)(myf0 >> 32), (uint)myf1, (uint)(myf1 >> 32)};
    }
    bpA = bqA; bpB = bqB;
  }

  // ---- finale ----
  WG_BARRIER();
  {
    float ps = 0.f;
#pragma unroll
    for (int j = 0; j < 8; j++) {
      ps += fp8val((uint)(myf0 >> (8 * j)) & 0xffu);
      ps += fp8val((uint)(myf1 >> (8 * j)) & 0xffu);
    }
    ps += __shfl_xor(ps, 16, 64);
    ps += __shfl_xor(ps, 32, 64);
    if (qg == 0) sredM[l15][w] = ps;  // partial sum over this wave's k-window, seq l15
  }
  // rm sums: wave w handles seqs 2w (lanes 0..31), 2w+1 (lanes 32..63)
  {
    int sq = 2 * w + (lane >> 5), tl = lane & 31;
    const float* rp = rm + (size_t)(grp * 16 + sq) * Tn;
    int ls = lenl[sq];
    float rs = 0.f;
#pragma unroll
    for (int k = 0; k < 16; k++) {
      int idx = tl + 32 * k;
      float v = rp[idx];
      rs += (idx < ls) ? v : 0.f;
    }
#pragma unroll
    for (int o = 1; o < 32; o <<= 1) rs += __shfl_xor(rs, o, 64);
    if ((lane & 31) == 0) rmsL[sq] = rs;
  }
  __syncthreads();
  if (t < 16) {  // wave 0, qg 0, l15 = t: holds L2acc/lenq for seq t
    float4 s0 = *(const float4*)&sredM[t][0];
    float4 s1 = *(const float4*)&sredM[t][4];
    float Ss = (s0.x + s0.y) + (s0.z + s0.w) + (s1.x + s1.y) + (s1.z + s1.w);
    outp[grp * 16 + t] = 0.6931471805599453f * L2acc - (float)lenq * 6.104793232414985f
                         + logf(Ss) + rmsL[t];
  }
}

extern "C" void kernel_launch(void* const* d_in, const int* in_sizes, int n_in,
                              void* d_out, int out_size, void* d_ws, size_t ws_size,
                              hipStream_t stream) {
  const float* seq = (const float*)d_in[0];
  const int* lens = (const int*)d_in[1];
  const float* px = (const float*)d_in[2];
  const float* py = (const float*)d_in[3];
  char* ws = (char*)d_ws;
  ushort* emitb = (ushort*)(ws + 0x0000000);
  float* rm     = (float*)(ws + 0x2000000);
  ushort* wmatb = (ushort*)(ws + 0x2020000);
  float* bias   = (float*)(ws + 0x2060000);
  float* rcsg   = (float*)(ws + 0x2062000);
  float* px0sp  = (float*)(ws + 0x2063000);
  u64* pq       = (u64*)(ws + 0x2070000);
  float* outp   = (float*)d_out;

  hipLaunchKernelGGL(k_prep, dim3(512), dim3(128), 0, stream, py, wmatb, bias);
  hipLaunchKernelGGL(k_pq, dim3(32), dim3(256), 0, stream, px, rcsg, px0sp, pq);
  hipLaunchKernelGGL(k_emit3, dim3(NT / 64), dim3(256), 0, stream, seq, wmatb, bias, rcsg, emitb, rm);
  hipLaunchKernelGGL(k_rec9, dim3(4), dim3(512), 0, stream, emitb, rm, pq, px0sp, lens, outp);
}

// Round 10
// 577.683 us; speedup vs baseline: 2.2728x; 1.0499x over previous
//
#include <hip/hip_runtime.h>
#include <stdint.h>

#define Hn 512
#define Dn 128
#define Nn 64
#define Tn 512
#define NT (Nn*Tn)   // 32768

typedef unsigned int uint;
typedef unsigned short ushort;
typedef unsigned long long u64;

typedef __attribute__((ext_vector_type(4))) float f32x4;
typedef __attribute__((ext_vector_type(8))) int i32x8;
typedef __attribute__((ext_vector_type(8))) short short8;   // 8 bf16 (4 VGPRs)

// lgkm-only barrier: orders all LDS traffic across the WG without draining vmcnt,
// so global prefetch loads stay in flight across barriers.
#define WG_BARRIER() asm volatile("s_waitcnt lgkmcnt(0)\n\ts_barrier" ::: "memory")

// 3-ary max helper (compiles to v_max3_f32)
__device__ inline float max3f(float a, float b, float c) { return fmaxf(fmaxf(a, b), c); }

// ---------- ws layout (bytes) ----------
// emitb : 0x0000000  NT*Hn*2  = 32 MB  (exp(emit-rowmax)*rcsg, bf16; cols PERMUTED:
//                    each k_rec lane's 16 values are one contiguous 32B run)
// rm    : 0x2000000  NT*4     = 128 KB
// wmatb : 0x2020000  Hn*Dn*2  = 128 KB (bf16 logit weights)
// bias  : 0x2060000  Hn*4     = 2 KB
// rcsg  : 0x2062000  Hn*4     (colmax/448)
// px0sp : 0x2063000  Hn*4     (px[0][j]*cs[j], stored PERMUTED like emitb)
// pq    : 0x2070000  256 KB   (P fp8 e4m3, K=128 MFMA A-frags, sigma-permuted byte order)

__device__ inline float bf2f(ushort u) { union { uint i; float f; } v; v.i = uint(u) << 16; return v.f; }
__device__ inline float ubits(uint u) { union { uint i; float f; } v; v.i = u; return v.f; }
__device__ inline ushort f2bf(float f) {
  union { uint i; float f; } v; v.f = f;
  uint u = v.i;
  uint r = (u + 0x7FFFu + ((u >> 16) & 1u)) >> 16;
  return ushort(r);
}
// e4m3fn decode (non-negative only); finale only
__device__ inline float fp8val(uint b) {
  uint e = (b >> 3) & 15u, m = b & 7u;
  return e ? ldexpf((float)(8u + m), (int)e - 10) : ldexpf((float)m, -9);
}
// pack 8 floats to 8 e4m3 bytes; the (position -> k) convention is defined by k_pq's
// sigma gather, applied identically to A and B so HW pairing cancels.
__device__ inline u64 pack8fp8(const float* v, float qs) {
  int lo = 0, hi = 0;
  lo = __builtin_amdgcn_cvt_pk_fp8_f32(v[0] * qs, v[1] * qs, lo, false);
  lo = __builtin_amdgcn_cvt_pk_fp8_f32(v[2] * qs, v[3] * qs, lo, true);
  hi = __builtin_amdgcn_cvt_pk_fp8_f32(v[4] * qs, v[5] * qs, hi, false);
  hi = __builtin_amdgcn_cvt_pk_fp8_f32(v[6] * qs, v[7] * qs, hi, true);
  return (u64)(uint)lo | ((u64)(uint)hi << 32);
}
// col permutation for emitb/px0sp: swap (mt, qg) 2-bit fields within each 64-block
__device__ inline int permcol(int c) {
  return (c & ~63) | ((c & 12) << 2) | ((c & 48) >> 2) | (c & 3);
}

// FUSED k_prep + colmax + P-quantize. Blocks 0..255: prep (2 rows of py each).
// Blocks 256..287: quantize m-tile (ntg = b-256) into sigma-permuted A-frag order:
// byte (qa, jj) of block kb <-> k = kb*128 + (qa>>1)*64 + ((jj>>2)&3)*16 + (qa&1)*8 + (jj>>4)*4 + (jj&3)
__global__ __launch_bounds__(256) void k_preppq(
    const float* __restrict__ py, const float* __restrict__ px,
    ushort* __restrict__ wmatb, float* __restrict__ bias,
    float* __restrict__ rcsg, float* __restrict__ px0sp, u64* __restrict__ pq) {
  __shared__ float ksl[512][17];   // 34 KB, padded stride
  __shared__ float pm[16][17];
  __shared__ float csL[16];
  __shared__ float s2[4];
  int b = blockIdx.x;
  int t = threadIdx.x;
  if (b < 256) {
    // ---- prep: rows 2b, 2b+1 of py ----
    int h = 2 * b + (t >> 7), d = t & 127;
    float p = py[h * Dn + d];
    float lp = logf(p), l1 = log1pf(-p);
    wmatb[h * Dn + d] = f2bf(lp - l1);   // logit, bf16 (A operand is exact 0/1)
    float v = l1;
    for (int o = 1; o < 64; o <<= 1) v += __shfl_xor(v, o, 64);
    if ((t & 63) == 0) s2[t >> 6] = v;
    __syncthreads();
    if ((t & 127) == 0) bias[h] = s2[(t >> 7) * 2] + s2[(t >> 7) * 2 + 1];
    return;
  }
  int ntg = b - 256;               // global m-tile 0..31
  for (int i = 0; i < 8; i++) {
    int q = i * 256 + t;           // float4 id over 512x16
    int row = q >> 2, c4 = q & 3;
    float4 v = *(const float4*)(px + (size_t)row * Hn + ntg * 16 + c4 * 4);
    ksl[row][c4 * 4 + 0] = v.x; ksl[row][c4 * 4 + 1] = v.y;
    ksl[row][c4 * 4 + 2] = v.z; ksl[row][c4 * 4 + 3] = v.w;
  }
  __syncthreads();
  // col-max of the staged 512x16 slice
  {
    int c = t & 15, ch = t >> 4;   // 16 chunks x 32 rows
    float m = 0.f;
#pragma unroll
    for (int r = 0; r < 30; r += 3) m = max3f(m, fmaxf(ksl[ch * 32 + r][c], ksl[ch * 32 + r + 1][c]), ksl[ch * 32 + r + 2][c]);
    m = max3f(m, ksl[ch * 32 + 30][c], ksl[ch * 32 + 31][c]);
    pm[ch][c] = m;
  }
  __syncthreads();
  if (t < 16) {
    float m = pm[0][t];
#pragma unroll
    for (int i = 1; i < 15; i += 2) m = max3f(m, pm[i][t], pm[i + 1][t]);
    m = fmaxf(m, pm[15][t]);
    float c = 448.0f / m;
    csL[t] = c;
    rcsg[ntg * 16 + t] = m * (1.0f / 448.0f);
    px0sp[permcol(ntg * 16 + t)] = px[ntg * 16 + t] * c;   // row 0 of px, pre-scaled
  }
  __syncthreads();
  int kb = t >> 6, lane = t & 63, qa = lane >> 4, c15 = lane & 15;
  float csv = csL[c15];
  int kbase = kb * 128 + (qa >> 1) * 64 + (qa & 1) * 8;
  size_t base = ((size_t)(((ntg >> 2) * 16 + kb * 4 + (ntg & 3)) * 64 + lane)) * 4;
#pragma unroll
  for (int d = 0; d < 4; d++) {
    float vv[8];
#pragma unroll
    for (int bb = 0; bb < 8; bb++) {
      int jj = d * 8 + bb;
      int kk = kbase + (((jj >> 2) & 3) << 4) + ((jj >> 4) << 2) + (jj & 3);
      vv[bb] = ksl[kk][c15];
    }
    pq[base + d] = pack8fp8(vv, csv);
  }
}

// FUSED emit GEMM (bf16 MFMA) + rowmax + exp + rcsg-scale + permuted eb store + rm store.
// B staged in 4 chunks of 128 rows -> 56 KB LDS -> 2 WGs/CU.
__global__ __launch_bounds__(256, 2) void k_emit3(
    const float* __restrict__ A, const ushort* __restrict__ wmatb,
    const float* __restrict__ bias, const float* __restrict__ rcsg,
    ushort* __restrict__ eb, float* __restrict__ rm) {
  __shared__ ushort Bs[128][136];   // 34816 B (one 128-row chunk of wmatb)
  __shared__ ushort As[64][136];    // 17408 B
  __shared__ float biasL[512];      // 2 KB
  __shared__ float rcsL[512];       // 2 KB
  int t = threadIdx.x;
  int r0 = blockIdx.x * 64;
  // stage A: 64 rows x 128 f32 -> bf16 (values 0/1: exact)
  for (int i = 0; i < 8; i++) {
    int q = i * 256 + t, row = q >> 5, c4 = q & 31;
    float4 v = *(const float4*)(A + (size_t)(r0 + row) * Dn + c4 * 4);
    ushort4 u4 = {f2bf(v.x), f2bf(v.y), f2bf(v.z), f2bf(v.w)};
    *(ushort4*)&As[row][c4 * 4] = u4;
  }
  biasL[t] = bias[t]; biasL[t + 256] = bias[t + 256];
  rcsL[t] = rcsg[t];  rcsL[t + 256] = rcsg[t + 256];
  __syncthreads();

  const int w = t >> 6, lane = t & 63, l15 = lane & 15, g4 = lane >> 4;
  // A fragments: row = w*16 + l15, k = kt*32 + g4*8 .. +8
  short8 afr[4];
#pragma unroll
  for (int kt = 0; kt < 4; kt++)
    afr[kt] = *(const short8*)&As[w * 16 + l15][kt * 32 + g4 * 8];

  f32x4 acc[32];
  for (int cc = 0; cc < 4; cc++) {
    __syncthreads();   // Bs free for overwrite
    for (int i = 0; i < 8; i++) {
      int q = i * 256 + t, row = q >> 4, c = q & 15;
      *(uint4*)&Bs[row][c * 8] = *(const uint4*)(wmatb + (cc * 128 + row) * 128 + c * 8);
    }
    __syncthreads();   // Bs staged
#pragma unroll
    for (int n8 = 0; n8 < 8; n8++) {
      int nt = cc * 8 + n8;
      f32x4 a = {0.f, 0.f, 0.f, 0.f};
#pragma unroll
      for (int kt = 0; kt < 4; kt++) {
        short8 bfr = *(const short8*)&Bs[n8 * 16 + l15][kt * 32 + g4 * 8];
        a = __builtin_amdgcn_mfma_f32_16x16x32_bf16(afr[kt], bfr, a, 0, 0, 0);
      }
      acc[nt] = a;
    }
  }
  // bias + per-row max (row = w*16 + g4*4 + r, col = nt*16 + l15)
  float mrow[4] = {-1e30f, -1e30f, -1e30f, -1e30f};
#pragma unroll
  for (int nt = 0; nt < 32; nt++) {
    float bv = biasL[nt * 16 + l15];
#pragma unroll
    for (int r = 0; r < 4; r++) {
      float v = acc[nt][r] + bv;
      acc[nt][r] = v;
      mrow[r] = fmaxf(mrow[r], v);
    }
  }
#pragma unroll
  for (int o = 1; o < 16; o <<= 1) {
    mrow[0] = fmaxf(mrow[0], __shfl_xor(mrow[0], o, 64));
    mrow[1] = fmaxf(mrow[1], __shfl_xor(mrow[1], o, 64));
    mrow[2] = fmaxf(mrow[2], __shfl_xor(mrow[2], o, 64));
    mrow[3] = fmaxf(mrow[3], __shfl_xor(mrow[3], o, 64));
  }
  if (l15 == 0) {
#pragma unroll
    for (int r = 0; r < 4; r++) rm[(size_t)(r0 + w * 16 + g4 * 4 + r)] = mrow[r];
  }
  // exp + scale + PERMUTED store
  ushort* ebase = eb + (size_t)(r0 + w * 16 + g4 * 4) * Hn;
#pragma unroll
  for (int nt = 0; nt < 32; nt++) {
    int colp = (nt >> 2) * 64 + (l15 >> 2) * 16 + (nt & 3) * 4 + (l15 & 3);
    float rc = rcsL[nt * 16 + l15];
#pragma unroll
    for (int r = 0; r < 4; r++) {
      float e = __expf(acc[nt][r] - mrow[r]) * rc;
      ebase[(size_t)r * Hn + colp] = f2bf(e);
    }
  }
}

// 4 WGs x 512 threads (8 waves). D = P(A) x alpha(B), sigma-permuted k-order.
// Lane (qg,l15) of wave w owns seq l15, cols {w*64 + mt*16 + qg*4 + r} — and packs
// those SAME 16 registers directly into its 16B BfI slot (no ut array, no transpose).
// BfI layout [slot16B][seq]: quantize write and MFMA read are both contiguous
// per-wave patterns (conflict-free).
__global__ __launch_bounds__(512, 2) void k_rec9(
    const ushort* __restrict__ eb, const float* __restrict__ rm,
    const u64* __restrict__ pq, const float* __restrict__ px0sp,
    const int* __restrict__ lens, float* __restrict__ outp) {
  const int grp = blockIdx.x;        // 0..3
  const int t = threadIdx.x;         // 0..511
  const int w = t >> 6;              // wave 0..7
  const int lane = t & 63, qg = lane >> 4, l15 = lane & 15;

  __shared__ uint4 BfI[32][16];      // alpha fp8 image [16B-slot][seq] (8 KB)
  __shared__ float sredM[16][12];    // per-seq per-wave partial max
  __shared__ float rmsL[16];
  __shared__ int lenl[16];

  // ---- persistent P fragments (A operand): wave w -> m-tiles 4w..4w+3 ----
  i32x8 PRv[16];
  {
    const uint4* pqv = (const uint4*)pq;
#pragma unroll
    for (int f = 0; f < 16; f++) {
      uint4 p0 = pqv[((size_t)(w * 16 + f) * 64 + lane) * 2 + 0];
      uint4 p1 = pqv[((size_t)(w * 16 + f) * 64 + lane) * 2 + 1];
      i32x8 v = {(int)p0.x, (int)p0.y, (int)p0.z, (int)p0.w,
                 (int)p1.x, (int)p1.y, (int)p1.z, (int)p1.w};
      PRv[f] = v;
    }
  }

  if (t < 16) lenl[t] = lens[grp * 16 + t];
  const size_t seqstride = (size_t)Tn * Hn;
  const ushort* myrow = eb + (size_t)(grp * 16 + l15) * seqstride + w * 64 + qg * 16;
  uint4* myslot = &BfI[w * 4 + qg][l15];

  float4 uv0, uv1, uv2, uv3;
  // ---- init: uv = px0sp * e' in the lane's natural (mt*4+r) order ----
  {
    uint4 e0 = *(const uint4*)myrow;
    uint4 e1 = *(const uint4*)(myrow + 8);
    float4 p0 = *(const float4*)(px0sp + w * 64 + qg * 16 + 0);
    float4 p1 = *(const float4*)(px0sp + w * 64 + qg * 16 + 4);
    float4 p2 = *(const float4*)(px0sp + w * 64 + qg * 16 + 8);
    float4 p3 = *(const float4*)(px0sp + w * 64 + qg * 16 + 12);
    uv0.x = p0.x * ubits(e0.x << 16);  uv0.y = p0.y * ubits(e0.x & 0xffff0000u);
    uv0.z = p0.z * ubits(e0.y << 16);  uv0.w = p0.w * ubits(e0.y & 0xffff0000u);
    uv1.x = p1.x * ubits(e0.z << 16);  uv1.y = p1.y * ubits(e0.z & 0xffff0000u);
    uv1.z = p1.z * ubits(e0.w << 16);  uv1.w = p1.w * ubits(e0.w & 0xffff0000u);
    uv2.x = p2.x * ubits(e1.x << 16);  uv2.y = p2.y * ubits(e1.x & 0xffff0000u);
    uv2.z = p2.z * ubits(e1.y << 16);  uv2.w = p2.w * ubits(e1.y & 0xffff0000u);
    uv3.x = p3.x * ubits(e1.z << 16);  uv3.y = p3.y * ubits(e1.z & 0xffff0000u);
    uv3.z = p3.z * ubits(e1.w << 16);  uv3.w = p3.w * ubits(e1.w & 0xffff0000u);
    float ma = max3f(max3f(uv0.x, uv0.y, uv0.z), max3f(uv0.w, uv1.x, uv1.y),
                     max3f(uv1.z, uv1.w, uv2.x));
    float mb = max3f(max3f(uv2.y, uv2.z, uv2.w), max3f(uv3.x, uv3.y, uv3.z), uv3.w);
    float mxv = fmaxf(ma, mb);
    mxv = fmaxf(mxv, __shfl_xor(mxv, 16, 64));
    mxv = fmaxf(mxv, __shfl_xor(mxv, 32, 64));
    if (qg == 0) sredM[l15][w] = mxv;
  }
  WG_BARRIER();
  const int t_end = lenl[15];
  const int lenq = lenl[l15];
  float L2acc;
  u64 myf0, myf1;

  // ---- step-0 quantize: pack OWN 16 registers into own slot ----
  {
    float4 g0 = *(const float4*)&sredM[l15][0];
    float4 g1 = *(const float4*)&sredM[l15][4];
    float gm = fmaxf(max3f(max3f(g0.x, g0.y, g0.z), max3f(g0.w, g1.x, g1.y), g1.z), g1.w);
    L2acc = __log2f(gm);
    float qs = 448.0f * __builtin_amdgcn_rcpf(gm);
    float v0[8] = {uv0.x, uv0.y, uv0.z, uv0.w, uv1.x, uv1.y, uv1.z, uv1.w};
    float v1[8] = {uv2.x, uv2.y, uv2.z, uv2.w, uv3.x, uv3.y, uv3.z, uv3.w};
    myf0 = pack8fp8(v0, qs);
    myf1 = pack8fp8(v1, qs);
    *myslot = (uint4){(uint)myf0, (uint)(myf0 >> 32), (uint)myf1, (uint)(myf1 >> 32)};
  }

  // ---- emit prefetch: one contiguous 32B per lane ----
  const ushort* epp = myrow + Hn;
  uint4 bpA = *(const uint4*)epp;
  uint4 bpB = *(const uint4*)(epp + 8);
  epp += Hn;

  // ---- recursion: 2 lgkm-only barriers/step ----
  for (int ts = 1; ts < t_end; ts++) {
    WG_BARRIER();  // BAR0: BfI published

    // hoist ALL 8 B-frag reads: 8 ds_read_b128 pipeline before the MFMA chain
    uint4 bfr[8];
#pragma unroll
    for (int s = 0; s < 8; s++) bfr[s] = BfI[(s >> 1) * 8 + qg * 2 + (s & 1)][l15];

    // MFMA: 4 k-blocks (K=128) x 4 m-tiles; A=P regs, B=alpha LDS
    f32x4 ac0 = {0.f, 0.f, 0.f, 0.f}, ac1 = {0.f, 0.f, 0.f, 0.f};
    f32x4 ac2 = {0.f, 0.f, 0.f, 0.f}, ac3 = {0.f, 0.f, 0.f, 0.f};
    __builtin_amdgcn_s_setprio(1);
#pragma unroll
    for (int kb = 0; kb < 4; kb++) {
      uint4 b0 = bfr[kb * 2 + 0];
      uint4 b1 = bfr[kb * 2 + 1];
      i32x8 bf = {(int)b0.x, (int)b0.y, (int)b0.z, (int)b0.w,
                  (int)b1.x, (int)b1.y, (int)b1.z, (int)b1.w};
      ac0 = __builtin_amdgcn_mfma_scale_f32_16x16x128_f8f6f4(
          PRv[kb * 4 + 0], bf, ac0, 0, 0, 0, 0x7F7F7F7F, 0, 0x7F7F7F7F);
      ac1 = __builtin_amdgcn_mfma_scale_f32_16x16x128_f8f6f4(
          PRv[kb * 4 + 1], bf, ac1, 0, 0, 0, 0x7F7F7F7F, 0, 0x7F7F7F7F);
      ac2 = __builtin_amdgcn_mfma_scale_f32_16x16x128_f8f6f4(
          PRv[kb * 4 + 2], bf, ac2, 0, 0, 0, 0x7F7F7F7F, 0, 0x7F7F7F7F);
      ac3 = __builtin_amdgcn_mfma_scale_f32_16x16x128_f8f6f4(
          PRv[kb * 4 + 3], bf, ac3, 0, 0, 0, 0x7F7F7F7F, 0, 0x7F7F7F7F);
    }
    __builtin_amdgcn_s_setprio(0);

    // prefetch emit(ts+1) AFTER the MFMA issue (off the pre-MFMA critical path)
    uint4 bqA = *(const uint4*)epp;
    uint4 bqB = *(const uint4*)(epp + 8);
    epp += Hn;

    // epilogue: u = acc * e' entirely in registers; per-seq max via max3 + 2 shfl
    {
      uv0.x = ac0[0] * ubits(bpA.x << 16);  uv0.y = ac0[1] * ubits(bpA.x & 0xffff0000u);
      uv0.z = ac0[2] * ubits(bpA.y << 16);  uv0.w = ac0[3] * ubits(bpA.y & 0xffff0000u);
      uv1.x = ac1[0] * ubits(bpA.z << 16);  uv1.y = ac1[1] * ubits(bpA.z & 0xffff0000u);
      uv1.z = ac1[2] * ubits(bpA.w << 16);  uv1.w = ac1[3] * ubits(bpA.w & 0xffff0000u);
      uv2.x = ac2[0] * ubits(bpB.x << 16);  uv2.y = ac2[1] * ubits(bpB.x & 0xffff0000u);
      uv2.z = ac2[2] * ubits(bpB.y << 16);  uv2.w = ac2[3] * ubits(bpB.y & 0xffff0000u);
      uv3.x = ac3[0] * ubits(bpB.z << 16);  uv3.y = ac3[1] * ubits(bpB.z & 0xffff0000u);
      uv3.z = ac3[2] * ubits(bpB.w << 16);  uv3.w = ac3[3] * ubits(bpB.w & 0xffff0000u);
      float ma = max3f(max3f(uv0.x, uv0.y, uv0.z), max3f(uv0.w, uv1.x, uv1.y),
                       max3f(uv1.z, uv1.w, uv2.x));
      float mb = max3f(max3f(uv2.y, uv2.z, uv2.w), max3f(uv3.x, uv3.y, uv3.z), uv3.w);
      float mxv = fmaxf(ma, mb);
      mxv = fmaxf(mxv, __shfl_xor(mxv, 16, 64));
      mxv = fmaxf(mxv, __shfl_xor(mxv, 32, 64));
      if (qg == 0) sredM[l15][w] = mxv;
    }
    WG_BARRIER();  // BAR1: sredM published (only cross-wave dependency)

    // quantize: pack OWN registers, write own slot (conflict-free contiguous write)
    if (ts < lenq) {
      float4 g0 = *(const float4*)&sredM[l15][0];
      float4 g1 = *(const float4*)&sredM[l15][4];
      float gm = fmaxf(max3f(max3f(g0.x, g0.y, g0.z), max3f(g0.w, g1.x, g1.y), g1.z), g1.w);
      L2acc += __log2f(gm);
      float qs = 448.0f * __builtin_amdgcn_rcpf(gm);
      float v0[8] = {uv0.x, uv0.y, uv0.z, uv0.w, uv1.x, uv1.y, uv1.z, uv1.w};
      float v1[8] = {uv2.x, uv2.y, uv2.z, uv2.w, uv3.x, uv3.y, uv3.z, uv3.w};
      myf0 = pack8fp8(v0, qs);
      myf1 = pack8fp8(v1, qs);
      *myslot = (uint4){(uint)myf0, (uint)(myf0 >> 32), (uint)myf1, (uint)(myf1 >> 32)};
    }
    bpA = bqA; bpB = bqB;
  }

  // ---- finale ----
  WG_BARRIER();
  {
    float ps = 0.f;
#pragma unroll
    for (int j = 0; j < 8; j++) {
      ps += fp8val((uint)(myf0 >> (8 * j)) & 0xffu);
      ps += fp8val((uint)(myf1 >> (8 * j)) & 0xffu);
    }
    ps += __shfl_xor(ps, 16, 64);
    ps += __shfl_xor(ps, 32, 64);
    if (qg == 0) sredM[l15][w] = ps;  // partial sum over this wave's k-window, seq l15
  }
  // rm sums: wave w handles seqs 2w (lanes 0..31), 2w+1 (lanes 32..63)
  {
    int sq = 2 * w + (lane >> 5), tl = lane & 31;
    const float* rp = rm + (size_t)(grp * 16 + sq) * Tn;
    int ls = lenl[sq];
    float rs = 0.f;
#pragma unroll
    for (int k = 0; k < 16; k++) {
      int idx = tl + 32 * k;
      float v = rp[idx];
      rs += (idx < ls) ? v : 0.f;
    }
#pragma unroll
    for (int o = 1; o < 32; o <<= 1) rs += __shfl_xor(rs, o, 64);
    if ((lane & 31) == 0) rmsL[sq] = rs;
  }
  __syncthreads();
  if (t < 16) {  // wave 0, qg 0, l15 = t: holds L2acc/lenq for seq t
    float4 s0 = *(const float4*)&sredM[t][0];
    float4 s1 = *(const float4*)&sredM[t][4];
    float Ss = (s0.x + s0.y) + (s0.z + s0.w) + (s1.x + s1.y) + (s1.z + s1.w);
    outp[grp * 16 + t] = 0.6931471805599453f * L2acc - (float)lenq * 6.104793232414985f
                         + logf(Ss) + rmsL[t];
  }
}

extern "C" void kernel_launch(void* const* d_in, const int* in_sizes, int n_in,
                              void* d_out, int out_size, void* d_ws, size_t ws_size,
                              hipStream_t stream) {
  const float* seq = (const float*)d_in[0];
  const int* lens = (const int*)d_in[1];
  const float* px = (const float*)d_in[2];
  const float* py = (const float*)d_in[3];
  char* ws = (char*)d_ws;
  ushort* emitb = (ushort*)(ws + 0x0000000);
  float* rm     = (float*)(ws + 0x2000000);
  ushort* wmatb = (ushort*)(ws + 0x2020000);
  float* bias   = (float*)(ws + 0x2060000);
  float* rcsg   = (float*)(ws + 0x2062000);
  float* px0sp  = (float*)(ws + 0x2063000);
  u64* pq       = (u64*)(ws + 0x2070000);
  float* outp   = (float*)d_out;

  hipLaunchKernelGGL(k_preppq, dim3(288), dim3(256), 0, stream, py, px, wmatb, bias, rcsg, px0sp, pq);
  hipLaunchKernelGGL(k_emit3, dim3(NT / 64), dim3(256), 0, stream, seq, wmatb, bias, rcsg, emitb, rm);
  hipLaunchKernelGGL(k_rec9, dim3(4), dim3(512), 0, stream, emitb, rm, pq, px0sp, lens, outp);
}